// Round 17
// baseline (279.352 us; speedup 1.0000x reference)
//
#include <hip/hip_runtime.h>

#define N_NODES 30000
#define E1 150000
#define EN 30000
#define ET 180000
#define LALPHA 0.2f
#define NB_SCAN 118

typedef unsigned int u32;
typedef unsigned short u16;
typedef __attribute__((ext_vector_type(8))) short short8;
typedef __attribute__((ext_vector_type(4))) short short4v;
typedef __attribute__((ext_vector_type(4))) float f32x4;

__device__ __forceinline__ float bf2f(u16 u){ return __uint_as_float(((u32)u)<<16); }
__device__ __forceinline__ float2 bfp2(u32 u){
  return make_float2(__uint_as_float(u<<16), __uint_as_float(u & 0xffff0000u));
}
__device__ __forceinline__ u16 f2bf(float f){
  u32 x = __float_as_uint(f);
  return (u16)((x + 0x7fffu + ((x>>16)&1u)) >> 16);
}
__device__ __forceinline__ u32 pk(float x, float y){
  return ((u32)f2bf(x)) | (((u32)f2bf(y))<<16);
}
__device__ __forceinline__ float wredf(float v){
  #pragma unroll
  for(int o=32;o>0;o>>=1) v += __shfl_xor(v, o, 64);
  return v;
}
__device__ __forceinline__ float eluf(float y){ return (y>0.f)? y : expm1f(y); }
// dtype dispatch: f==1 -> buffers are f32; f==0 -> packed bf16
__device__ __forceinline__ float ld1(const void* p, int i, int f){
  return f ? ((const float*)p)[i] : bf2f(((const u16*)p)[i]);
}
__device__ __forceinline__ float2 ldp(const void* p, int i, int f){ // elements 2i,2i+1
  if(f){ return ((const float2*)p)[i]; }
  return bfp2(((const u32*)p)[i]);
}
__device__ __forceinline__ void st1(void* p, int i, float v, int f){
  if(f) ((float*)p)[i] = v; else ((u16*)p)[i] = f2bf(v);
}

__device__ __forceinline__ short8 frag_zero(){
  short8 r;
  #pragma unroll
  for(int i=0;i<8;i++) r[i]=0;
  return r;
}
// packed-bf16 fragment load (8 consecutive bf16, 2x8B vector loads)
__device__ __forceinline__ short8 ldfragb(const u16* p, int idx){
  short8 r;
  short4v lo = *(const short4v*)(p+idx);
  short4v hi = *(const short4v*)(p+idx+4);
  #pragma unroll
  for(int i=0;i<4;i++){ r[i]=lo[i]; r[4+i]=hi[i]; }
  return r;
}
// 16B-aligned fragment load (one dwordx4)
__device__ __forceinline__ short8 ldfragb16(const u16* p, int idx){
  return *(const short8*)(p+idx);
}
__device__ __forceinline__ short8 ldfragb_p4(const u16* p, int idx){
  short8 r=frag_zero();
  short4v lo = *(const short4v*)(p+idx);
  #pragma unroll
  for(int i=0;i<4;i++) r[i]=lo[i];
  return r;
}
// dual-dtype fragment loads (f32 path: contiguous scalar loads, compiler merges)
__device__ __forceinline__ short8 ldfrag(const void* p, int idx, int f){
  short8 r;
  if(f){
    const float* fp=(const float*)p+idx;
    #pragma unroll
    for(int i=0;i<8;i++) r[i]=(short)f2bf(fp[i]);
  } else {
    return ldfragb((const u16*)p, idx);
  }
  return r;
}
__device__ __forceinline__ short8 ldfrag_p4(const void* p, int idx, int f){
  short8 r=frag_zero();
  if(f){
    const float* fp=(const float*)p+idx;
    #pragma unroll
    for(int i=0;i<4;i++) r[i]=(short)f2bf(fp[i]);
  } else {
    return ldfragb_p4((const u16*)p, idx);
  }
  return r;
}

// Detect dtype: for bf16-packed data, low u16 of each u32 is a bf16 of ~N(0,1)
__global__ void k_detect(const u32* x, int* flag){
  int t = threadIdx.x;
  int c = 0;
  #pragma unroll
  for(int i=0;i<4;i++){
    u32 v = x[t*4+i];
    u32 lo = v & 0xffffu;
    u32 e = (lo>>7)&0xffu;
    c += (lo==0u || (e>=100u && e<=140u)) ? 1 : 0;
  }
  __shared__ int sd[256];
  sd[t]=c; __syncthreads();
  for(int o=128;o>0;o>>=1){ if(t<o) sd[t]+=sd[t+o]; __syncthreads(); }
  if(t==0) *flag = (sd[0] > 512) ? 0 : 1;
}

// one-time bf16 pre-pack: ent (3M), ah (60K), ao (120K), and (f32 case) ee (15M)
__global__ void k_prep(const void* ent, const void* ah, const void* ao, const void* ee,
                       u16* entB, u16* ahB, u16* aoB, u16* eeB, int ws_ok, const int* flag){
  int f = *flag;
  int gid = blockIdx.x*256 + threadIdx.x;
  int stride = gridDim.x*256;
  const int T0=750000, T1=765000, T2=795000, T3=795000+3750000; // 4-elem groups
  int lim = (f && ws_ok) ? T3 : T2;
  for(int i=gid; i<lim; i+=stride){
    const void* src; u16* dst; int g;
    if(i<T0){ src=ent; dst=entB; g=i; }
    else if(i<T1){ src=ah; dst=ahB; g=i-T0; }
    else if(i<T2){ src=ao; dst=aoB; g=i-T1; }
    else { src=ee; dst=eeB; g=i-T2; }
    if(f){
      float4 v = ((const float4*)src)[g];
      short4v o;
      o[0]=(short)f2bf(v.x); o[1]=(short)f2bf(v.y);
      o[2]=(short)f2bf(v.z); o[3]=(short)f2bf(v.w);
      ((short4v*)dst)[g] = o;
    } else {
      ((short4v*)dst)[g] = ((const short4v*)src)[g];
    }
  }
}

// out_relation = relation_embed @ W  (200x100)@(100x200): f32 ws + tail of d_out
__global__ void k_outrel(const void* rel, const void* W, float* outrel, void* out, const int* flag){
  int f = *flag;
  int t = blockIdx.x*blockDim.x + threadIdx.x;
  if(t >= 200*200) return;
  int r = t / 200, j = t - r*200;
  float acc = 0.f;
  for(int k=0;k<100;k++) acc += ld1(rel, r*100+k, f) * ld1(W, k*200+j, f);
  outrel[t] = acc;
  st1(out, 6000000 + t, acc, f);
}

// b1[i<600]: b1[hd*300+k] = sum_j a2h[hd][j]*ah[hd][j][k]
// b2[i-600]: b2[k] = sum_j a2o[j]*ao[j][k]   (k<600)
__global__ void k_small_b(const void* ah, const void* a2h, const void* ao, const void* a2o,
                          float* b1, float* b2, const int* flag){
  int f = *flag;
  int i = blockIdx.x*4 + (threadIdx.x>>6);
  int L = threadIdx.x & 63;
  if(i >= 1200) return;
  float a = 0.f;
  if(i < 600){
    int hd = i/300, k = i - hd*300;
    for(int j=L; j<100; j+=64)
      a += ld1(a2h, hd*100+j, f) * ld1(ah, hd*30000 + j*300 + k, f);
    a = wredf(a);
    if(L==0) b1[i] = a;
  } else {
    int k = i - 600;
    for(int j=L; j<200; j+=64)
      a += ld1(a2o, j, f) * ld1(ao, j*600 + k, f);
    a = wredf(a);
    if(L==0) b2[k] = a;
  }
}

// c1[i<400]: c1[hd*200+r] = sum_k b1[hd*300+200+k]*rel[r][k]
// c2[i-400]: c2[r] = sum_k b2[400+k]*outrel[r][k]
__global__ void k_small_c(const void* rel, const float* outrel, const float* b1, const float* b2,
                          float* c1, float* c2, const int* flag){
  int f = *flag;
  int i = blockIdx.x*4 + (threadIdx.x>>6);
  int L = threadIdx.x & 63;
  if(i >= 600) return;
  float a = 0.f;
  if(i < 400){
    int hd = i/200, r = i - hd*200;
    for(int k=L; k<100; k+=64)
      a += b1[hd*300+200+k] * ld1(rel, r*100+k, f);
    a = wredf(a);
    if(L==0) c1[i] = a;
  } else {
    int r = i - 400;
    for(int k=L; k<200; k+=64)
      a += b2[400+k] * outrel[r*200+k];
    a = wredf(a);
    if(L==0) c2[r] = a;
  }
}

__global__ void k_count(const int* src1, const int* srcN, int* cnt){
  int e = blockIdx.x*256 + threadIdx.x;
  if(e>=ET) return;
  int s = (e<E1)? src1[e] : srcN[e-E1];
  atomicAdd(&cnt[s],1);
}

// two-level scan: per-block scan -> block sums scan -> fixup
__global__ void k_scan1(const int* cnt, int* ofs, int* bsum){
  __shared__ int sd[256];
  int b=blockIdx.x, t=threadIdx.x;
  int idx=b*256+t;
  int v=(idx<N_NODES)? cnt[idx] : 0;
  sd[t]=v; __syncthreads();
  for(int o=1;o<256;o<<=1){
    int u=(t>=o)? sd[t-o]:0;
    __syncthreads();
    sd[t]+=u; __syncthreads();
  }
  if(idx<N_NODES) ofs[idx]=sd[t]-v;
  if(t==255) bsum[b]=sd[255];
}

__global__ void k_scan2(const int* bsum, int* bstart, int* ofs){
  __shared__ int sd[128];
  int t=threadIdx.x;
  int v=(t<NB_SCAN)? bsum[t]:0;
  sd[t]=v; __syncthreads();
  for(int o=1;o<128;o<<=1){
    int u=(t>=o)? sd[t-o]:0;
    __syncthreads();
    sd[t]+=u; __syncthreads();
  }
  if(t<NB_SCAN) bstart[t]=sd[t]-v;
  if(t==127) ofs[N_NODES]=sd[127];
}

__global__ void k_scan3(int* ofs, int* cur, const int* bstart){
  int b=blockIdx.x, t=threadIdx.x;
  int idx=b*256+t;
  if(idx>=N_NODES) return;
  int v = ofs[idx] + bstart[b];
  ofs[idx]=v; cur[idx]=v;
}

// scatter + CSR side tables: einfo[p]=(e,d,t0,t1) (t1=-1 for orig), pos[e]=p
__global__ void k_scatter(const int* src1, const int* dst1, const int* srcN, const int* dstN,
                          const int* et, const int* etn, int* cur, int* pos, int4* einfo){
  int e = blockIdx.x*256 + threadIdx.x;
  if(e>=ET) return;
  int s,d,t0,t1;
  if(e<E1){ s=src1[e]; d=dst1[e]; t0=et[e]; t1=-1; }
  else { int en=e-E1; s=srcN[en]; d=dstN[en]; t0=etn[en*2]; t1=etn[en*2+1]; }
  int p = atomicAdd(&cur[s],1);
  pos[e]=p;
  einfo[p]=make_int4(e,d,t0,t1);
}

// per-node dots layer1 (bf16 node features): q1[n*4 + {h0s,h0d,h1s,h1d}]
__global__ void k_q1(const u32* entB2, const float* b1, float* q1){
  int n = blockIdx.x*4 + (threadIdx.x>>6);
  if(n>=N_NODES) return;
  int L = threadIdx.x & 63;
  float d00=0,d01=0,d10=0,d11=0;
  if(L<50){
    float2 xv = bfp2(entB2[n*50+L]);
    int k0=2*L;
    d00 = xv.x*b1[k0]     + xv.y*b1[k0+1];
    d01 = xv.x*b1[100+k0] + xv.y*b1[100+k0+1];
    d10 = xv.x*b1[300+k0] + xv.y*b1[300+k0+1];
    d11 = xv.x*b1[400+k0] + xv.y*b1[400+k0+1];
  }
  d00=wredf(d00); d01=wredf(d01); d10=wredf(d10); d11=wredf(d11);
  if(L==0){ q1[n*4+0]=d00; q1[n*4+1]=d01; q1[n*4+2]=d10; q1[n*4+3]=d11; }
}

// layer1 edge logits for original edges: MFMA GEMV, 32 edges/wave, writes w1c in CSR order
__global__ __launch_bounds__(256) void k_edge1g(const void* ee, const u16* eeB, int ws_ok,
    const int* src1, const int* dst1, const float* b1, const float* q1,
    const int* pos, float* w1c, const int* flag){
  int f = *flag;
  const void* eeP = (f && ws_ok) ? (const void*)eeB : ee;
  int fe = (f && ws_ok) ? 0 : f;
  int wid = threadIdx.x>>6, l = threadIdx.x&63;
  int lr = l&15, lg = l>>4;
  int m0 = blockIdx.x*128 + wid*32;
  short8 bfr[4];
  #pragma unroll
  for(int ks=0;ks<4;ks++){
    int kb = ks*32 + lg*8;
    short8 b = frag_zero();
    if(lr<2){
      const float* bp = b1 + (lr==0? 200:500);
      #pragma unroll
      for(int i=0;i<8;i++){ int k=kb+i; if(k<100) b[i]=(short)f2bf(bp[k]); }
    }
    bfr[ks]=b;
  }
  int row0 = m0 + lr, row1 = m0 + 16 + lr;
  bool ok0 = row0 < E1, ok1 = row1 < E1;
  f32x4 acc0=(f32x4){0,0,0,0}, acc1=(f32x4){0,0,0,0};
  #pragma unroll
  for(int ks=0;ks<4;ks++){
    int kb = ks*32 + lg*8;
    short8 a0 = frag_zero(), a1 = frag_zero();
    if(ok0){
      if(kb+8<=100) a0 = ldfrag(eeP, row0*100+kb, fe);
      else if(kb<100) a0 = ldfrag_p4(eeP, row0*100+kb, fe);
    }
    if(ok1){
      if(kb+8<=100) a1 = ldfrag(eeP, row1*100+kb, fe);
      else if(kb<100) a1 = ldfrag_p4(eeP, row1*100+kb, fe);
    }
    acc0 = __builtin_amdgcn_mfma_f32_16x16x32_bf16(a0, bfr[ks], acc0, 0,0,0);
    acc1 = __builtin_amdgcn_mfma_f32_16x16x32_bf16(a1, bfr[ks], acc1, 0,0,0);
  }
  if(lr<2){
    #pragma unroll
    for(int mi=0;mi<2;mi++){
      #pragma unroll
      for(int r=0;r<4;r++){
        int e = m0 + mi*16 + lg*4 + r;
        if(e<E1){
          float rv = (mi==0)? acc0[r] : acc1[r];
          int s=src1[e], d=dst1[e];
          float p = q1[s*4+lr*2] + q1[d*4+lr*2+1] + rv;
          p = (p>=0.f)? p : LALPHA*p;
          w1c[2*pos[e] + lr] = expf(-p);
        }
      }
    }
  }
}

// layer1 edge logits for nhop edges (CSR-ordered writes)
__global__ void k_edge1b(const int* etn, const int* srcN, const int* dstN,
                         const float* c1, const float* q1, const int* pos, float* w1c){
  int en = blockIdx.x*256+threadIdx.x;
  if(en>=EN) return;
  int t0=etn[en*2], t1=etn[en*2+1];
  float r0 = c1[t0]+c1[t1];
  float r1 = c1[200+t0]+c1[200+t1];
  int s=srcN[en], d=dstN[en];
  float p0 = q1[s*4+0]+q1[d*4+1]+r0;
  float p1 = q1[s*4+2]+q1[d*4+3]+r1;
  p0=(p0>=0.f)?p0:LALPHA*p0;
  p1=(p1>=0.f)?p1:LALPHA*p1;
  int p = pos[E1+en];
  w1c[2*p]   = expf(-p0);
  w1c[2*p+1] = expf(-p1);
}

// layer1 gather (einfo-driven, x4 unroll): G1[hd][n][200]
__global__ void k_acc1(const int* ofs, const int4* einfo,
                       const u32* entB2, const void* ee, const u32* eeB32, int ws_ok,
                       const void* rel,
                       const float2* w1c, u32* Gq, float* rs1, const int* flag){
  int f = *flag;
  int use_pack = (f==1) && ws_ok;
  int n = blockIdx.x*4 + (threadIdx.x>>6);
  if(n>=N_NODES) return;
  int L = threadIdx.x & 63;
  int beg = ofs[n], end = ofs[n+1];
  float av0x=0,av0y=0,av1x=0,av1y=0, aw0x=0,aw0y=0,aw1x=0,aw1y=0;
  float r0=0, r1=0;
  int i = beg;
  for(; i+3<end; i+=4){
    int4 ei[4]; float2 w[4];
    #pragma unroll
    for(int u=0;u<4;u++) ei[u]=einfo[i+u];
    #pragma unroll
    for(int u=0;u<4;u++) w[u]=w1c[i+u];
    r0 += w[0].x+w[1].x+w[2].x+w[3].x;
    r1 += w[0].y+w[1].y+w[2].y+w[3].y;
    if(L<50){
      float2 xv[4], vv[4];
      #pragma unroll
      for(int u=0;u<4;u++) xv[u]=bfp2(entB2[ei[u].y*50+L]);
      #pragma unroll
      for(int u=0;u<4;u++){
        if(ei[u].x < E1){
          vv[u] = use_pack? bfp2(eeB32[ei[u].x*50+L]) : ldp(ee, ei[u].x*50+L, f);
        } else {
          float2 a=ldp(rel,ei[u].z*50+L,f), b=ldp(rel,ei[u].w*50+L,f);
          vv[u]=make_float2(a.x+b.x, a.y+b.y);
        }
      }
      #pragma unroll
      for(int u=0;u<4;u++){
        av0x += w[u].x*xv[u].x; av0y += w[u].x*xv[u].y;
        av1x += w[u].y*xv[u].x; av1y += w[u].y*xv[u].y;
        aw0x += w[u].x*vv[u].x; aw0y += w[u].x*vv[u].y;
        aw1x += w[u].y*vv[u].x; aw1y += w[u].y*vv[u].y;
      }
    }
  }
  for(; i<end; ++i){
    int4 ei = einfo[i];
    float2 wa = w1c[i];
    r0 += wa.x; r1 += wa.y;
    if(L<50){
      float2 x0 = bfp2(entB2[ei.y*50+L]);
      float2 v0;
      if(ei.x < E1){ v0 = use_pack? bfp2(eeB32[ei.x*50+L]) : ldp(ee, ei.x*50+L, f); }
      else {
        float2 a=ldp(rel,ei.z*50+L,f), b=ldp(rel,ei.w*50+L,f);
        v0=make_float2(a.x+b.x, a.y+b.y);
      }
      av0x += wa.x*x0.x; av0y += wa.x*x0.y;
      av1x += wa.y*x0.x; av1y += wa.y*x0.y;
      aw0x += wa.x*v0.x; aw0y += wa.x*v0.y;
      aw1x += wa.y*v0.x; aw1y += wa.y*v0.y;
    }
  }
  float i0 = (r0==0.f)? 0.f : 1.f/r0;
  float i1 = (r1==0.f)? 0.f : 1.f/r1;
  if(L<50){
    u32* g0 = Gq + n*100;
    u32* g1 = Gq + 3000000 + n*100;
    g0[L]    = pk(av0x*i0, av0y*i0);
    g0[50+L] = pk(aw0x*i0, aw0y*i0);
    g1[L]    = pk(av1x*i1, av1y*i1);
    g1[50+L] = pk(aw1x*i1, aw1y*i1);
  }
  if(L==0){ rs1[n]=r0; rs1[N_NODES+n]=r1; }
}

// MFMA node GEMM layer1, M=32/block, N-split across waves; h written into Gx2 rows [0..200)
__global__ __launch_bounds__(256) void k_gemm1m(const u16* G, const u16* ahB, const u16* entB,
                        const float* rs1, u16* Gx2){
  int hd = blockIdx.y;
  int wid = threadIdx.x>>6, l = threadIdx.x&63;
  int lr = l&15, lg = l>>4;
  int m0 = blockIdx.x*32;
  int row0 = m0 + lr, row1 = m0 + 16 + lr;
  bool hi_ok = (m0+16) < N_NODES;
  const u16* Gh0 = G + hd*6000000 + row0*200;
  const u16* Gh1 = G + hd*6000000 + row1*200;
  const u16* A = ahB + hd*30000;
  f32x4 acc[2][2];
  #pragma unroll
  for(int mi=0;mi<2;mi++)
    #pragma unroll
    for(int ntl=0;ntl<2;ntl++) acc[mi][ntl]=(f32x4){0.f,0.f,0.f,0.f};
  #pragma unroll
  for(int k0=0;k0<100;k0+=32){
    int kb = k0 + lg*8;
    short8 a0 = (kb+8<=100)? ldfragb(entB, row0*100+kb)
              : (kb<100    ? ldfragb_p4(entB, row0*100+kb) : frag_zero());
    short8 a1 = frag_zero();
    if(hi_ok){
      if(kb+8<=100) a1 = ldfragb(entB, row1*100+kb);
      else if(kb<100) a1 = ldfragb_p4(entB, row1*100+kb);
    }
    #pragma unroll
    for(int ntl=0;ntl<2;ntl++){
      int j = (ntl*4+wid)*16 + lr;
      short8 b = frag_zero();
      if(j<100){
        if(kb+8<=100) b = ldfragb(A, j*300 + kb);
        else if(kb<100) b = ldfragb_p4(A, j*300 + kb);
      }
      acc[0][ntl] = __builtin_amdgcn_mfma_f32_16x16x32_bf16(a0, b, acc[0][ntl], 0,0,0);
      acc[1][ntl] = __builtin_amdgcn_mfma_f32_16x16x32_bf16(a1, b, acc[1][ntl], 0,0,0);
    }
  }
  #pragma unroll
  for(int k0=0;k0<200;k0+=32){
    int kb = k0 + lg*8;
    short8 a0 = (kb+8<=200)? ldfragb(Gh0, kb) : frag_zero();
    short8 a1 = (hi_ok && kb+8<=200)? ldfragb(Gh1, kb) : frag_zero();
    #pragma unroll
    for(int ntl=0;ntl<2;ntl++){
      int j = (ntl*4+wid)*16 + lr;
      short8 b = (j<100 && kb+8<=200)? ldfragb(A, j*300 + 100 + kb) : frag_zero();
      acc[0][ntl] = __builtin_amdgcn_mfma_f32_16x16x32_bf16(a0, b, acc[0][ntl], 0,0,0);
      acc[1][ntl] = __builtin_amdgcn_mfma_f32_16x16x32_bf16(a1, b, acc[1][ntl], 0,0,0);
    }
  }
  #pragma unroll
  for(int mi=0;mi<2;mi++){
    if(mi==1 && !hi_ok) break;
    #pragma unroll
    for(int r=0;r<4;r++){
      int rr = m0 + mi*16 + lg*4 + r;
      float sc = (rs1[hd*N_NODES+rr]==0.f)? 0.f : 1.f;
      #pragma unroll
      for(int ntl=0;ntl<2;ntl++){
        int j = (ntl*4+wid)*16 + lr;
        if(j<100) Gx2[rr*600 + hd*100 + j] = f2bf(eluf(acc[mi][ntl][r]*sc));
      }
    }
  }
}

// q2 over h stored in Gx2 rows [0..200)
__global__ void k_q2(const uint2* hq, const float* b2, float* q2){
  int n = blockIdx.x*4 + (threadIdx.x>>6);
  if(n>=N_NODES) return;
  int L = threadIdx.x&63;
  float ds=0, dd=0;
  if(L<50){
    uint2 hv = hq[n*150+L];
    float2 a = bfp2(hv.x);
    float2 b = bfp2(hv.y);
    int k0=4*L;
    ds = a.x*b2[k0]+a.y*b2[k0+1]+b.x*b2[k0+2]+b.y*b2[k0+3];
    dd = a.x*b2[200+k0]+a.y*b2[200+k0+1]+b.x*b2[200+k0+2]+b.y*b2[200+k0+3];
  }
  ds=wredf(ds); dd=wredf(dd);
  if(L==0){ q2[n*2]=ds; q2[n*2+1]=dd; }
}

__global__ void k_edge2(const int* src1,const int* dst1,const int* srcN,const int* dstN,
                        const int* et, const int* etn, const float* c2, const float* q2,
                        const int* pos, float* w2c){
  int e = blockIdx.x*256+threadIdx.x;
  if(e>=ET) return;
  int s,d; float r;
  if(e<E1){ s=src1[e]; d=dst1[e]; r = c2[et[e]]; }
  else { int en=e-E1; s=srcN[en]; d=dstN[en]; r = c2[etn[en*2]]+c2[etn[en*2+1]]; }
  float p = q2[s*2] + q2[d*2+1] + r;
  p = (p>=0.f)? p : LALPHA*p;
  w2c[pos[e]] = expf(-p);
}

// layer2 gather (einfo-driven, x4 unroll): writes Gx2 rows [200..600)
__global__ void k_acc2(const int* ofs, const int4* einfo,
                       u32* Gx2u, const float4* or4, const float* w2c,
                       float* rs2){
  const uint2* h2 = (const uint2*)Gx2u;
  int n = blockIdx.x*4 + (threadIdx.x>>6);
  if(n>=N_NODES) return;
  int L = threadIdx.x&63;
  int beg=ofs[n], end=ofs[n+1];
  float rv=0;
  float avx=0,avy=0,avz=0,avw=0, awx=0,awy=0,awz=0,aww=0;
  int i=beg;
  for(; i+3<end; i+=4){
    int4 ei[4]; float wv[4];
    #pragma unroll
    for(int u=0;u<4;u++) ei[u]=einfo[i+u];
    #pragma unroll
    for(int u=0;u<4;u++) wv[u]=w2c[i+u];
    rv += wv[0]+wv[1]+wv[2]+wv[3];
    if(L<50){
      float2 ha[4], hb[4]; float4 o[4];
      #pragma unroll
      for(int u=0;u<4;u++){ uint2 hv = h2[ei[u].y*150+L]; ha[u]=bfp2(hv.x); hb[u]=bfp2(hv.y); }
      #pragma unroll
      for(int u=0;u<4;u++){
        float4 a = or4[ei[u].z*50+L];
        if(ei[u].w >= 0){
          float4 b = or4[ei[u].w*50+L];
          a = make_float4(a.x+b.x, a.y+b.y, a.z+b.z, a.w+b.w);
        }
        o[u]=a;
      }
      #pragma unroll
      for(int u=0;u<4;u++){
        avx += wv[u]*ha[u].x; avy += wv[u]*ha[u].y;
        avz += wv[u]*hb[u].x; avw += wv[u]*hb[u].y;
        awx += wv[u]*o[u].x;  awy += wv[u]*o[u].y;
        awz += wv[u]*o[u].z;  aww += wv[u]*o[u].w;
      }
    }
  }
  for(; i<end; ++i){
    int4 ei = einfo[i];
    float w0 = w2c[i];
    rv += w0;
    if(L<50){
      uint2 hv = h2[ei.y*150+L];
      float2 ha0=bfp2(hv.x), hb0=bfp2(hv.y);
      float4 o0 = or4[ei.z*50+L];
      if(ei.w >= 0){
        float4 b = or4[ei.w*50+L];
        o0 = make_float4(o0.x+b.x, o0.y+b.y, o0.z+b.z, o0.w+b.w);
      }
      avx += w0*ha0.x; avy += w0*ha0.y; avz += w0*hb0.x; avw += w0*hb0.y;
      awx += w0*o0.x; awy += w0*o0.y; awz += w0*o0.z; aww += w0*o0.w;
    }
  }
  float inv = (rv==0.f)? 0.f : 1.f/rv;
  if(L<50){
    u32* g = Gx2u + n*300 + 100;
    g[2*L]       = pk(avx*inv, avy*inv);
    g[2*L+1]     = pk(avz*inv, avw*inv);
    g[100+2*L]   = pk(awx*inv, awy*inv);
    g[100+2*L+1] = pk(awz*inv, aww*inv);
  }
  if(L==0) rs2[n]=rv;
}

// MFMA node GEMM layer2, M=32/block, LDS-staged A+B tiles; TAIL-GUARDED epilogue
__global__ __launch_bounds__(256) void k_gemm2m(const u16* Gx2, const u16* aoB,
                        const float* rs2, void* out, const int* flag){
  int f = *flag;
  __shared__ u16 As[32][36];   // 32 rows x 32k, row stride 36 u16 (72B)
  __shared__ u16 Bs[200][36];  // 200 rows x 32k
  int t = threadIdx.x;
  int wid = t>>6, l = t&63;
  int lr = l&15, lg = l>>4;
  int m0 = blockIdx.x*32;
  bool hi_ok = (m0+16) < N_NODES;   // rows m0..m0+15 always valid; m0+16.. only if hi_ok
  f32x4 acc[2][4];
  #pragma unroll
  for(int mi=0;mi<2;mi++)
    #pragma unroll
    for(int ntl=0;ntl<4;ntl++) acc[mi][ntl]=(f32x4){0.f,0.f,0.f,0.f};
  for(int k0=0;k0<600;k0+=32){
    int klen = (600-k0>=32)? 32 : (600-k0);   // 32 or 24
    int words = klen>>1;                       // 16 or 12
    // stage A tile (32 rows, row index clamped for OOB tail) and B tile (200 rows)
    for(int idx=t; idx<32*words; idx+=256){
      int r = idx/words, w = idx - r*words;
      int rr = m0 + r; if(rr >= N_NODES) rr = N_NODES-1;
      u32 v = *(const u32*)(Gx2 + rr*600 + k0 + 2*w);
      *(u32*)&As[r][2*w] = v;
    }
    for(int idx=t; idx<200*words; idx+=256){
      int r = idx/words, w = idx - r*words;
      u32 v = *(const u32*)(aoB + r*600 + k0 + 2*w);
      *(u32*)&Bs[r][2*w] = v;
    }
    __syncthreads();
    int kb = lg*8;
    bool kok = (kb+8<=klen);
    short8 a0 = frag_zero(), a1 = frag_zero();
    if(kok){
      a0 = ldfragb(&As[lr][0], kb);
      a1 = ldfragb(&As[16+lr][0], kb);
    }
    #pragma unroll
    for(int ntl=0;ntl<4;ntl++){
      int j = (ntl*4+wid)*16 + lr;
      short8 b = (j<200 && kok)? ldfragb(&Bs[0][0], j*36 + kb) : frag_zero();
      acc[0][ntl] = __builtin_amdgcn_mfma_f32_16x16x32_bf16(a0, b, acc[0][ntl], 0,0,0);
      acc[1][ntl] = __builtin_amdgcn_mfma_f32_16x16x32_bf16(a1, b, acc[1][ntl], 0,0,0);
    }
    __syncthreads();
  }
  #pragma unroll
  for(int mi=0;mi<2;mi++){
    if(mi==1 && !hi_ok) break;
    #pragma unroll
    for(int r=0;r<4;r++){
      int rr = m0 + mi*16 + lg*4 + r;
      float sc = (rs2[rr]==0.f)? 0.f : 1.f;
      #pragma unroll
      for(int ntl=0;ntl<4;ntl++){
        int j = (ntl*4+wid)*16 + lr;
        if(j<200) st1(out, rr*200 + j, eluf(acc[mi][ntl][r]*sc), f);
      }
    }
  }
}

extern "C" void kernel_launch(void* const* d_in, const int* in_sizes, int n_in,
                              void* d_out, int out_size, void* d_ws, size_t ws_size,
                              hipStream_t stream) {
  const void* ent = d_in[0];
  const void* rel = d_in[1];
  const int* el  = (const int*)d_in[2];
  const int* et  = (const int*)d_in[3];
  const void* ee  = d_in[4];
  const int* eln = (const int*)d_in[5];
  const int* etn = (const int*)d_in[6];
  const void* ah  = d_in[8];
  const void* a2h = d_in[9];
  const void* W   = d_in[10];
  const void* ao  = d_in[11];
  const void* a2o = d_in[12];

  float* wsf    = (float*)d_ws;
  int*   flag   = (int*)wsf;            // @0 (4 floats reserved)
  float* outrel = wsf+4;                // 40000
  float* b1     = wsf+40008;            // 600
  float* b2     = wsf+40608;            // 600
  float* c1     = wsf+41208;            // 400
  float* c2     = wsf+41608;            // 200
  float* q1     = wsf+41808;            // 120000
  float* q2     = wsf+161808;           // 60000
  float* w1c    = wsf+221808;           // 360000 (CSR-ordered float2 pairs)
  float* w2c    = wsf+581808;           // 180000 (CSR-ordered)
  float* rs1    = wsf+761808;           // 60000
  float* rs2    = wsf+821808;           // 30000
  int*   ofs    = (int*)(wsf+851808);   // 30001
  int*   cnt    = ofs+30001;            // 30000
  int*   cur    = cnt+30000;            // 30000
  int*   bsum   = (int*)(wsf+1121812);  // 128
  int*   bstart = bsum+128;             // 128 -> ends @ 1122068
  u16*   G      = (u16*)(wsf+1122072);  // G1: 12,000,000 u16 -> ends @ 7122072
  int*   pos    = (int*)(wsf+7122072);  // 180000 -> ends @ 7302072
  int4*  einfo  = (int4*)(wsf+7302072); // 180000 int4 -> ends @ 8022072 (16B aligned)
  u16*   entB   = (u16*)(wsf+10122072); // 3,000,000 u16 -> ends @ 11622072
  u16*   ahB    = (u16*)(wsf+11622072); // 60,000 u16 -> ends @ 11652072
  u16*   aoB    = (u16*)(wsf+11652072); // 120,000 u16 -> ends @ 11712072
  u16*   eeB    = (u16*)(wsf+11712072); // 15,000,000 u16
  // Gx2 (18M u16 = [h|v|w] rows of 600) ALIASES eeB region: eeB's last reader (k_acc1)
  // completes before k_gemm1m writes Gx2 (stream-ordered).
  u16*   Gx2    = (u16*)(wsf+11712072); // 18,000,000 u16 -> ends @ float 20712072 (~82.9 MB)
  int ws_ok = (ws_size >= (size_t)20712072*4) ? 1 : 0;

  const int* src1 = el;
  const int* dst1 = el + E1;
  const int* srcN = eln;
  const int* dstN = eln + EN;

  k_detect<<<1,256,0,stream>>>((const u32*)ent, flag);
  hipMemsetAsync(cnt, 0, 30000*sizeof(int), stream);
  k_prep<<<2048,256,0,stream>>>(ent, ah, ao, ee, entB, ahB, aoB, eeB, ws_ok, flag);
  k_small_b<<<300,256,0,stream>>>(ah,a2h,ao,a2o,b1,b2,flag);
  k_outrel<<<(200*200+255)/256,256,0,stream>>>(rel, W, outrel, d_out, flag);
  k_small_c<<<150,256,0,stream>>>(rel, outrel, b1, b2, c1, c2, flag);
  k_count<<<(ET+255)/256,256,0,stream>>>(src1, srcN, cnt);
  k_scan1<<<NB_SCAN,256,0,stream>>>(cnt, ofs, bsum);
  k_scan2<<<1,128,0,stream>>>(bsum, bstart, ofs);
  k_scan3<<<NB_SCAN,256,0,stream>>>(ofs, cur, bstart);
  k_scatter<<<(ET+255)/256,256,0,stream>>>(src1, dst1, srcN, dstN, et, etn, cur, pos, einfo);
  k_q1<<<(N_NODES+3)/4,256,0,stream>>>((const u32*)entB, b1, q1);
  k_edge1g<<<(E1+127)/128,256,0,stream>>>(ee, eeB, ws_ok, src1, dst1, b1, q1, pos, w1c, flag);
  k_edge1b<<<(EN+255)/256,256,0,stream>>>(etn, srcN, dstN, c1, q1, pos, w1c);
  k_acc1<<<(N_NODES+3)/4,256,0,stream>>>(ofs, einfo,
                                         (const u32*)entB, ee, (const u32*)eeB, ws_ok,
                                         rel, (const float2*)w1c, (u32*)G, rs1, flag);
  dim3 g1grid((N_NODES+31)/32, 2);
  k_gemm1m<<<g1grid,256,0,stream>>>(G, ahB, entB, rs1, Gx2);
  k_q2<<<(N_NODES+3)/4,256,0,stream>>>((const uint2*)Gx2, b2, q2);
  k_edge2<<<(ET+255)/256,256,0,stream>>>(src1, dst1, srcN, dstN, et, etn, c2, q2, pos, w2c);
  k_acc2<<<(N_NODES+3)/4,256,0,stream>>>(ofs, einfo,
                                         (u32*)Gx2, (const float4*)outrel, w2c, rs2);
  k_gemm2m<<<(N_NODES+31)/32,256,0,stream>>>(Gx2, aoB, rs2, d_out, flag);
}

// Round 18
// 244.739 us; speedup vs baseline: 1.1414x; 1.1414x over previous
//
#include <hip/hip_runtime.h>

#define N_NODES 30000
#define E1 150000
#define EN 30000
#define ET 180000
#define LALPHA 0.2f
#define NB_SCAN 118

typedef unsigned int u32;
typedef unsigned short u16;
typedef __attribute__((ext_vector_type(8))) short short8;
typedef __attribute__((ext_vector_type(4))) short short4v;
typedef __attribute__((ext_vector_type(4))) float f32x4;

__device__ __forceinline__ float bf2f(u16 u){ return __uint_as_float(((u32)u)<<16); }
__device__ __forceinline__ float2 bfp2(u32 u){
  return make_float2(__uint_as_float(u<<16), __uint_as_float(u & 0xffff0000u));
}
__device__ __forceinline__ u16 f2bf(float f){
  u32 x = __float_as_uint(f);
  return (u16)((x + 0x7fffu + ((x>>16)&1u)) >> 16);
}
__device__ __forceinline__ u32 pk(float x, float y){
  return ((u32)f2bf(x)) | (((u32)f2bf(y))<<16);
}
__device__ __forceinline__ float wredf(float v){
  #pragma unroll
  for(int o=32;o>0;o>>=1) v += __shfl_xor(v, o, 64);
  return v;
}
__device__ __forceinline__ float eluf(float y){ return (y>0.f)? y : expm1f(y); }
// dtype dispatch: f==1 -> buffers are f32; f==0 -> packed bf16
__device__ __forceinline__ float ld1(const void* p, int i, int f){
  return f ? ((const float*)p)[i] : bf2f(((const u16*)p)[i]);
}
__device__ __forceinline__ float2 ldp(const void* p, int i, int f){ // elements 2i,2i+1
  if(f){ return ((const float2*)p)[i]; }
  return bfp2(((const u32*)p)[i]);
}
__device__ __forceinline__ void st1(void* p, int i, float v, int f){
  if(f) ((float*)p)[i] = v; else ((u16*)p)[i] = f2bf(v);
}

__device__ __forceinline__ short8 frag_zero(){
  short8 r;
  #pragma unroll
  for(int i=0;i<8;i++) r[i]=0;
  return r;
}
// packed-bf16 fragment load (8 consecutive bf16, 2x8B vector loads)
__device__ __forceinline__ short8 ldfragb(const u16* p, int idx){
  short8 r;
  short4v lo = *(const short4v*)(p+idx);
  short4v hi = *(const short4v*)(p+idx+4);
  #pragma unroll
  for(int i=0;i<4;i++){ r[i]=lo[i]; r[4+i]=hi[i]; }
  return r;
}
// 16B-aligned fragment load (one dwordx4)
__device__ __forceinline__ short8 ldfragb16(const u16* p, int idx){
  return *(const short8*)(p+idx);
}
__device__ __forceinline__ short8 ldfragb_p4(const u16* p, int idx){
  short8 r=frag_zero();
  short4v lo = *(const short4v*)(p+idx);
  #pragma unroll
  for(int i=0;i<4;i++) r[i]=lo[i];
  return r;
}
// dual-dtype fragment loads (f32 path: contiguous scalar loads, compiler merges)
__device__ __forceinline__ short8 ldfrag(const void* p, int idx, int f){
  short8 r;
  if(f){
    const float* fp=(const float*)p+idx;
    #pragma unroll
    for(int i=0;i<8;i++) r[i]=(short)f2bf(fp[i]);
  } else {
    return ldfragb((const u16*)p, idx);
  }
  return r;
}
__device__ __forceinline__ short8 ldfrag_p4(const void* p, int idx, int f){
  short8 r=frag_zero();
  if(f){
    const float* fp=(const float*)p+idx;
    #pragma unroll
    for(int i=0;i<4;i++) r[i]=(short)f2bf(fp[i]);
  } else {
    return ldfragb_p4((const u16*)p, idx);
  }
  return r;
}

// Detect dtype: for bf16-packed data, low u16 of each u32 is a bf16 of ~N(0,1)
__global__ void k_detect(const u32* x, int* flag){
  int t = threadIdx.x;
  int c = 0;
  #pragma unroll
  for(int i=0;i<4;i++){
    u32 v = x[t*4+i];
    u32 lo = v & 0xffffu;
    u32 e = (lo>>7)&0xffu;
    c += (lo==0u || (e>=100u && e<=140u)) ? 1 : 0;
  }
  __shared__ int sd[256];
  sd[t]=c; __syncthreads();
  for(int o=128;o>0;o>>=1){ if(t<o) sd[t]+=sd[t+o]; __syncthreads(); }
  if(t==0) *flag = (sd[0] > 512) ? 0 : 1;
}

// one-time bf16 pre-pack: ent (3M), ah (60K), ao (120K), and (f32 case) ee (15M)
__global__ void k_prep(const void* ent, const void* ah, const void* ao, const void* ee,
                       u16* entB, u16* ahB, u16* aoB, u16* eeB, int ws_ok, const int* flag){
  int f = *flag;
  int gid = blockIdx.x*256 + threadIdx.x;
  int stride = gridDim.x*256;
  const int T0=750000, T1=765000, T2=795000, T3=795000+3750000; // 4-elem groups
  int lim = (f && ws_ok) ? T3 : T2;
  for(int i=gid; i<lim; i+=stride){
    const void* src; u16* dst; int g;
    if(i<T0){ src=ent; dst=entB; g=i; }
    else if(i<T1){ src=ah; dst=ahB; g=i-T0; }
    else if(i<T2){ src=ao; dst=aoB; g=i-T1; }
    else { src=ee; dst=eeB; g=i-T2; }
    if(f){
      float4 v = ((const float4*)src)[g];
      short4v o;
      o[0]=(short)f2bf(v.x); o[1]=(short)f2bf(v.y);
      o[2]=(short)f2bf(v.z); o[3]=(short)f2bf(v.w);
      ((short4v*)dst)[g] = o;
    } else {
      ((short4v*)dst)[g] = ((const short4v*)src)[g];
    }
  }
}

// out_relation = relation_embed @ W  (200x100)@(100x200): f32 ws + tail of d_out
__global__ void k_outrel(const void* rel, const void* W, float* outrel, void* out, const int* flag){
  int f = *flag;
  int t = blockIdx.x*blockDim.x + threadIdx.x;
  if(t >= 200*200) return;
  int r = t / 200, j = t - r*200;
  float acc = 0.f;
  for(int k=0;k<100;k++) acc += ld1(rel, r*100+k, f) * ld1(W, k*200+j, f);
  outrel[t] = acc;
  st1(out, 6000000 + t, acc, f);
}

// b1[i<600]: b1[hd*300+k] = sum_j a2h[hd][j]*ah[hd][j][k]
// b2[i-600]: b2[k] = sum_j a2o[j]*ao[j][k]   (k<600)
__global__ void k_small_b(const void* ah, const void* a2h, const void* ao, const void* a2o,
                          float* b1, float* b2, const int* flag){
  int f = *flag;
  int i = blockIdx.x*4 + (threadIdx.x>>6);
  int L = threadIdx.x & 63;
  if(i >= 1200) return;
  float a = 0.f;
  if(i < 600){
    int hd = i/300, k = i - hd*300;
    for(int j=L; j<100; j+=64)
      a += ld1(a2h, hd*100+j, f) * ld1(ah, hd*30000 + j*300 + k, f);
    a = wredf(a);
    if(L==0) b1[i] = a;
  } else {
    int k = i - 600;
    for(int j=L; j<200; j+=64)
      a += ld1(a2o, j, f) * ld1(ao, j*600 + k, f);
    a = wredf(a);
    if(L==0) b2[k] = a;
  }
}

// c1[i<400]: c1[hd*200+r] = sum_k b1[hd*300+200+k]*rel[r][k]
// c2[i-400]: c2[r] = sum_k b2[400+k]*outrel[r][k]
__global__ void k_small_c(const void* rel, const float* outrel, const float* b1, const float* b2,
                          float* c1, float* c2, const int* flag){
  int f = *flag;
  int i = blockIdx.x*4 + (threadIdx.x>>6);
  int L = threadIdx.x & 63;
  if(i >= 600) return;
  float a = 0.f;
  if(i < 400){
    int hd = i/200, r = i - hd*200;
    for(int k=L; k<100; k+=64)
      a += b1[hd*300+200+k] * ld1(rel, r*100+k, f);
    a = wredf(a);
    if(L==0) c1[i] = a;
  } else {
    int r = i - 400;
    for(int k=L; k<200; k+=64)
      a += b2[400+k] * outrel[r*200+k];
    a = wredf(a);
    if(L==0) c2[r] = a;
  }
}

__global__ void k_count(const int* src1, const int* srcN, int* cnt){
  int e = blockIdx.x*256 + threadIdx.x;
  if(e>=ET) return;
  int s = (e<E1)? src1[e] : srcN[e-E1];
  atomicAdd(&cnt[s],1);
}

// two-level scan: per-block scan -> block sums scan -> fixup
__global__ void k_scan1(const int* cnt, int* ofs, int* bsum){
  __shared__ int sd[256];
  int b=blockIdx.x, t=threadIdx.x;
  int idx=b*256+t;
  int v=(idx<N_NODES)? cnt[idx] : 0;
  sd[t]=v; __syncthreads();
  for(int o=1;o<256;o<<=1){
    int u=(t>=o)? sd[t-o]:0;
    __syncthreads();
    sd[t]+=u; __syncthreads();
  }
  if(idx<N_NODES) ofs[idx]=sd[t]-v;
  if(t==255) bsum[b]=sd[255];
}

__global__ void k_scan2(const int* bsum, int* bstart, int* ofs){
  __shared__ int sd[128];
  int t=threadIdx.x;
  int v=(t<NB_SCAN)? bsum[t]:0;
  sd[t]=v; __syncthreads();
  for(int o=1;o<128;o<<=1){
    int u=(t>=o)? sd[t-o]:0;
    __syncthreads();
    sd[t]+=u; __syncthreads();
  }
  if(t<NB_SCAN) bstart[t]=sd[t]-v;
  if(t==127) ofs[N_NODES]=sd[127];
}

__global__ void k_scan3(int* ofs, int* cur, const int* bstart){
  int b=blockIdx.x, t=threadIdx.x;
  int idx=b*256+t;
  if(idx>=N_NODES) return;
  int v = ofs[idx] + bstart[b];
  ofs[idx]=v; cur[idx]=v;
}

// scatter + CSR side tables: einfo[p]=(e,d,t0,t1) (t1=-1 for orig), pos[e]=p
__global__ void k_scatter(const int* src1, const int* dst1, const int* srcN, const int* dstN,
                          const int* et, const int* etn, int* cur, int* pos, int4* einfo){
  int e = blockIdx.x*256 + threadIdx.x;
  if(e>=ET) return;
  int s,d,t0,t1;
  if(e<E1){ s=src1[e]; d=dst1[e]; t0=et[e]; t1=-1; }
  else { int en=e-E1; s=srcN[en]; d=dstN[en]; t0=etn[en*2]; t1=etn[en*2+1]; }
  int p = atomicAdd(&cur[s],1);
  pos[e]=p;
  einfo[p]=make_int4(e,d,t0,t1);
}

// per-node dots layer1 (bf16 node features): q1[n*4 + {h0s,h0d,h1s,h1d}]
__global__ void k_q1(const u32* entB2, const float* b1, float* q1){
  int n = blockIdx.x*4 + (threadIdx.x>>6);
  if(n>=N_NODES) return;
  int L = threadIdx.x & 63;
  float d00=0,d01=0,d10=0,d11=0;
  if(L<50){
    float2 xv = bfp2(entB2[n*50+L]);
    int k0=2*L;
    d00 = xv.x*b1[k0]     + xv.y*b1[k0+1];
    d01 = xv.x*b1[100+k0] + xv.y*b1[100+k0+1];
    d10 = xv.x*b1[300+k0] + xv.y*b1[300+k0+1];
    d11 = xv.x*b1[400+k0] + xv.y*b1[400+k0+1];
  }
  d00=wredf(d00); d01=wredf(d01); d10=wredf(d10); d11=wredf(d11);
  if(L==0){ q1[n*4+0]=d00; q1[n*4+1]=d01; q1[n*4+2]=d10; q1[n*4+3]=d11; }
}

// layer1 edge logits for original edges: MFMA GEMV, 32 edges/wave, writes w1c in CSR order
__global__ __launch_bounds__(256) void k_edge1g(const void* ee, const u16* eeB, int ws_ok,
    const int* src1, const int* dst1, const float* b1, const float* q1,
    const int* pos, float* w1c, const int* flag){
  int f = *flag;
  const void* eeP = (f && ws_ok) ? (const void*)eeB : ee;
  int fe = (f && ws_ok) ? 0 : f;
  int wid = threadIdx.x>>6, l = threadIdx.x&63;
  int lr = l&15, lg = l>>4;
  int m0 = blockIdx.x*128 + wid*32;
  short8 bfr[4];
  #pragma unroll
  for(int ks=0;ks<4;ks++){
    int kb = ks*32 + lg*8;
    short8 b = frag_zero();
    if(lr<2){
      const float* bp = b1 + (lr==0? 200:500);
      #pragma unroll
      for(int i=0;i<8;i++){ int k=kb+i; if(k<100) b[i]=(short)f2bf(bp[k]); }
    }
    bfr[ks]=b;
  }
  int row0 = m0 + lr, row1 = m0 + 16 + lr;
  bool ok0 = row0 < E1, ok1 = row1 < E1;
  f32x4 acc0=(f32x4){0,0,0,0}, acc1=(f32x4){0,0,0,0};
  #pragma unroll
  for(int ks=0;ks<4;ks++){
    int kb = ks*32 + lg*8;
    short8 a0 = frag_zero(), a1 = frag_zero();
    if(ok0){
      if(kb+8<=100) a0 = ldfrag(eeP, row0*100+kb, fe);
      else if(kb<100) a0 = ldfrag_p4(eeP, row0*100+kb, fe);
    }
    if(ok1){
      if(kb+8<=100) a1 = ldfrag(eeP, row1*100+kb, fe);
      else if(kb<100) a1 = ldfrag_p4(eeP, row1*100+kb, fe);
    }
    acc0 = __builtin_amdgcn_mfma_f32_16x16x32_bf16(a0, bfr[ks], acc0, 0,0,0);
    acc1 = __builtin_amdgcn_mfma_f32_16x16x32_bf16(a1, bfr[ks], acc1, 0,0,0);
  }
  if(lr<2){
    #pragma unroll
    for(int mi=0;mi<2;mi++){
      #pragma unroll
      for(int r=0;r<4;r++){
        int e = m0 + mi*16 + lg*4 + r;
        if(e<E1){
          float rv = (mi==0)? acc0[r] : acc1[r];
          int s=src1[e], d=dst1[e];
          float p = q1[s*4+lr*2] + q1[d*4+lr*2+1] + rv;
          p = (p>=0.f)? p : LALPHA*p;
          w1c[2*pos[e] + lr] = expf(-p);
        }
      }
    }
  }
}

// layer1 edge logits for nhop edges (CSR-ordered writes)
__global__ void k_edge1b(const int* etn, const int* srcN, const int* dstN,
                         const float* c1, const float* q1, const int* pos, float* w1c){
  int en = blockIdx.x*256+threadIdx.x;
  if(en>=EN) return;
  int t0=etn[en*2], t1=etn[en*2+1];
  float r0 = c1[t0]+c1[t1];
  float r1 = c1[200+t0]+c1[200+t1];
  int s=srcN[en], d=dstN[en];
  float p0 = q1[s*4+0]+q1[d*4+1]+r0;
  float p1 = q1[s*4+2]+q1[d*4+3]+r1;
  p0=(p0>=0.f)?p0:LALPHA*p0;
  p1=(p1>=0.f)?p1:LALPHA*p1;
  int p = pos[E1+en];
  w1c[2*p]   = expf(-p0);
  w1c[2*p+1] = expf(-p1);
}

// layer1 gather (einfo-driven, x4 unroll): G1[hd][n][200]
__global__ void k_acc1(const int* ofs, const int4* einfo,
                       const u32* entB2, const void* ee, const u32* eeB32, int ws_ok,
                       const void* rel,
                       const float2* w1c, u32* Gq, float* rs1, const int* flag){
  int f = *flag;
  int use_pack = (f==1) && ws_ok;
  int n = blockIdx.x*4 + (threadIdx.x>>6);
  if(n>=N_NODES) return;
  int L = threadIdx.x & 63;
  int beg = ofs[n], end = ofs[n+1];
  float av0x=0,av0y=0,av1x=0,av1y=0, aw0x=0,aw0y=0,aw1x=0,aw1y=0;
  float r0=0, r1=0;
  int i = beg;
  for(; i+3<end; i+=4){
    int4 ei[4]; float2 w[4];
    #pragma unroll
    for(int u=0;u<4;u++) ei[u]=einfo[i+u];
    #pragma unroll
    for(int u=0;u<4;u++) w[u]=w1c[i+u];
    r0 += w[0].x+w[1].x+w[2].x+w[3].x;
    r1 += w[0].y+w[1].y+w[2].y+w[3].y;
    if(L<50){
      float2 xv[4], vv[4];
      #pragma unroll
      for(int u=0;u<4;u++) xv[u]=bfp2(entB2[ei[u].y*50+L]);
      #pragma unroll
      for(int u=0;u<4;u++){
        if(ei[u].x < E1){
          vv[u] = use_pack? bfp2(eeB32[ei[u].x*50+L]) : ldp(ee, ei[u].x*50+L, f);
        } else {
          float2 a=ldp(rel,ei[u].z*50+L,f), b=ldp(rel,ei[u].w*50+L,f);
          vv[u]=make_float2(a.x+b.x, a.y+b.y);
        }
      }
      #pragma unroll
      for(int u=0;u<4;u++){
        av0x += w[u].x*xv[u].x; av0y += w[u].x*xv[u].y;
        av1x += w[u].y*xv[u].x; av1y += w[u].y*xv[u].y;
        aw0x += w[u].x*vv[u].x; aw0y += w[u].x*vv[u].y;
        aw1x += w[u].y*vv[u].x; aw1y += w[u].y*vv[u].y;
      }
    }
  }
  for(; i<end; ++i){
    int4 ei = einfo[i];
    float2 wa = w1c[i];
    r0 += wa.x; r1 += wa.y;
    if(L<50){
      float2 x0 = bfp2(entB2[ei.y*50+L]);
      float2 v0;
      if(ei.x < E1){ v0 = use_pack? bfp2(eeB32[ei.x*50+L]) : ldp(ee, ei.x*50+L, f); }
      else {
        float2 a=ldp(rel,ei.z*50+L,f), b=ldp(rel,ei.w*50+L,f);
        v0=make_float2(a.x+b.x, a.y+b.y);
      }
      av0x += wa.x*x0.x; av0y += wa.x*x0.y;
      av1x += wa.y*x0.x; av1y += wa.y*x0.y;
      aw0x += wa.x*v0.x; aw0y += wa.x*v0.y;
      aw1x += wa.y*v0.x; aw1y += wa.y*v0.y;
    }
  }
  float i0 = (r0==0.f)? 0.f : 1.f/r0;
  float i1 = (r1==0.f)? 0.f : 1.f/r1;
  if(L<50){
    u32* g0 = Gq + n*100;
    u32* g1 = Gq + 3000000 + n*100;
    g0[L]    = pk(av0x*i0, av0y*i0);
    g0[50+L] = pk(aw0x*i0, aw0y*i0);
    g1[L]    = pk(av1x*i1, av1y*i1);
    g1[50+L] = pk(aw1x*i1, aw1y*i1);
  }
  if(L==0){ rs1[n]=r0; rs1[N_NODES+n]=r1; }
}

// MFMA node GEMM layer1, M=32/block, N-split across waves; h written into Gx2 rows [0..200)
__global__ __launch_bounds__(256) void k_gemm1m(const u16* G, const u16* ahB, const u16* entB,
                        const float* rs1, u16* Gx2){
  int hd = blockIdx.y;
  int wid = threadIdx.x>>6, l = threadIdx.x&63;
  int lr = l&15, lg = l>>4;
  int m0 = blockIdx.x*32;
  int row0 = m0 + lr, row1 = m0 + 16 + lr;
  bool hi_ok = (m0+16) < N_NODES;
  const u16* Gh0 = G + hd*6000000 + row0*200;
  const u16* Gh1 = G + hd*6000000 + row1*200;
  const u16* A = ahB + hd*30000;
  f32x4 acc[2][2];
  #pragma unroll
  for(int mi=0;mi<2;mi++)
    #pragma unroll
    for(int ntl=0;ntl<2;ntl++) acc[mi][ntl]=(f32x4){0.f,0.f,0.f,0.f};
  #pragma unroll
  for(int k0=0;k0<100;k0+=32){
    int kb = k0 + lg*8;
    short8 a0 = (kb+8<=100)? ldfragb(entB, row0*100+kb)
              : (kb<100    ? ldfragb_p4(entB, row0*100+kb) : frag_zero());
    short8 a1 = frag_zero();
    if(hi_ok){
      if(kb+8<=100) a1 = ldfragb(entB, row1*100+kb);
      else if(kb<100) a1 = ldfragb_p4(entB, row1*100+kb);
    }
    #pragma unroll
    for(int ntl=0;ntl<2;ntl++){
      int j = (ntl*4+wid)*16 + lr;
      short8 b = frag_zero();
      if(j<100){
        if(kb+8<=100) b = ldfragb(A, j*300 + kb);
        else if(kb<100) b = ldfragb_p4(A, j*300 + kb);
      }
      acc[0][ntl] = __builtin_amdgcn_mfma_f32_16x16x32_bf16(a0, b, acc[0][ntl], 0,0,0);
      acc[1][ntl] = __builtin_amdgcn_mfma_f32_16x16x32_bf16(a1, b, acc[1][ntl], 0,0,0);
    }
  }
  #pragma unroll
  for(int k0=0;k0<200;k0+=32){
    int kb = k0 + lg*8;
    short8 a0 = (kb+8<=200)? ldfragb(Gh0, kb) : frag_zero();
    short8 a1 = (hi_ok && kb+8<=200)? ldfragb(Gh1, kb) : frag_zero();
    #pragma unroll
    for(int ntl=0;ntl<2;ntl++){
      int j = (ntl*4+wid)*16 + lr;
      short8 b = (j<100 && kb+8<=200)? ldfragb(A, j*300 + 100 + kb) : frag_zero();
      acc[0][ntl] = __builtin_amdgcn_mfma_f32_16x16x32_bf16(a0, b, acc[0][ntl], 0,0,0);
      acc[1][ntl] = __builtin_amdgcn_mfma_f32_16x16x32_bf16(a1, b, acc[1][ntl], 0,0,0);
    }
  }
  #pragma unroll
  for(int mi=0;mi<2;mi++){
    if(mi==1 && !hi_ok) break;
    #pragma unroll
    for(int r=0;r<4;r++){
      int rr = m0 + mi*16 + lg*4 + r;
      float sc = (rs1[hd*N_NODES+rr]==0.f)? 0.f : 1.f;
      #pragma unroll
      for(int ntl=0;ntl<2;ntl++){
        int j = (ntl*4+wid)*16 + lr;
        if(j<100) Gx2[rr*600 + hd*100 + j] = f2bf(eluf(acc[mi][ntl][r]*sc));
      }
    }
  }
}

// q2 over h stored in Gx2 rows [0..200)
__global__ void k_q2(const uint2* hq, const float* b2, float* q2){
  int n = blockIdx.x*4 + (threadIdx.x>>6);
  if(n>=N_NODES) return;
  int L = threadIdx.x&63;
  float ds=0, dd=0;
  if(L<50){
    uint2 hv = hq[n*150+L];
    float2 a = bfp2(hv.x);
    float2 b = bfp2(hv.y);
    int k0=4*L;
    ds = a.x*b2[k0]+a.y*b2[k0+1]+b.x*b2[k0+2]+b.y*b2[k0+3];
    dd = a.x*b2[200+k0]+a.y*b2[200+k0+1]+b.x*b2[200+k0+2]+b.y*b2[200+k0+3];
  }
  ds=wredf(ds); dd=wredf(dd);
  if(L==0){ q2[n*2]=ds; q2[n*2+1]=dd; }
}

__global__ void k_edge2(const int* src1,const int* dst1,const int* srcN,const int* dstN,
                        const int* et, const int* etn, const float* c2, const float* q2,
                        const int* pos, float* w2c){
  int e = blockIdx.x*256+threadIdx.x;
  if(e>=ET) return;
  int s,d; float r;
  if(e<E1){ s=src1[e]; d=dst1[e]; r = c2[et[e]]; }
  else { int en=e-E1; s=srcN[en]; d=dstN[en]; r = c2[etn[en*2]]+c2[etn[en*2+1]]; }
  float p = q2[s*2] + q2[d*2+1] + r;
  p = (p>=0.f)? p : LALPHA*p;
  w2c[pos[e]] = expf(-p);
}

// layer2 gather (einfo-driven, x4 unroll): writes Gx2 rows [200..600)
__global__ void k_acc2(const int* ofs, const int4* einfo,
                       u32* Gx2u, const float4* or4, const float* w2c,
                       float* rs2){
  const uint2* h2 = (const uint2*)Gx2u;
  int n = blockIdx.x*4 + (threadIdx.x>>6);
  if(n>=N_NODES) return;
  int L = threadIdx.x&63;
  int beg=ofs[n], end=ofs[n+1];
  float rv=0;
  float avx=0,avy=0,avz=0,avw=0, awx=0,awy=0,awz=0,aww=0;
  int i=beg;
  for(; i+3<end; i+=4){
    int4 ei[4]; float wv[4];
    #pragma unroll
    for(int u=0;u<4;u++) ei[u]=einfo[i+u];
    #pragma unroll
    for(int u=0;u<4;u++) wv[u]=w2c[i+u];
    rv += wv[0]+wv[1]+wv[2]+wv[3];
    if(L<50){
      float2 ha[4], hb[4]; float4 o[4];
      #pragma unroll
      for(int u=0;u<4;u++){ uint2 hv = h2[ei[u].y*150+L]; ha[u]=bfp2(hv.x); hb[u]=bfp2(hv.y); }
      #pragma unroll
      for(int u=0;u<4;u++){
        float4 a = or4[ei[u].z*50+L];
        if(ei[u].w >= 0){
          float4 b = or4[ei[u].w*50+L];
          a = make_float4(a.x+b.x, a.y+b.y, a.z+b.z, a.w+b.w);
        }
        o[u]=a;
      }
      #pragma unroll
      for(int u=0;u<4;u++){
        avx += wv[u]*ha[u].x; avy += wv[u]*ha[u].y;
        avz += wv[u]*hb[u].x; avw += wv[u]*hb[u].y;
        awx += wv[u]*o[u].x;  awy += wv[u]*o[u].y;
        awz += wv[u]*o[u].z;  aww += wv[u]*o[u].w;
      }
    }
  }
  for(; i<end; ++i){
    int4 ei = einfo[i];
    float w0 = w2c[i];
    rv += w0;
    if(L<50){
      uint2 hv = h2[ei.y*150+L];
      float2 ha0=bfp2(hv.x), hb0=bfp2(hv.y);
      float4 o0 = or4[ei.z*50+L];
      if(ei.w >= 0){
        float4 b = or4[ei.w*50+L];
        o0 = make_float4(o0.x+b.x, o0.y+b.y, o0.z+b.z, o0.w+b.w);
      }
      avx += w0*ha0.x; avy += w0*ha0.y; avz += w0*hb0.x; avw += w0*hb0.y;
      awx += w0*o0.x; awy += w0*o0.y; awz += w0*o0.z; aww += w0*o0.w;
    }
  }
  float inv = (rv==0.f)? 0.f : 1.f/rv;
  if(L<50){
    u32* g = Gx2u + n*300 + 100;
    g[2*L]       = pk(avx*inv, avy*inv);
    g[2*L+1]     = pk(avz*inv, avw*inv);
    g[100+2*L]   = pk(awx*inv, awy*inv);
    g[100+2*L+1] = pk(awz*inv, aww*inv);
  }
  if(L==0) rs2[n]=rv;
}

// MFMA node GEMM layer2, M=32/block, single contiguous K=600: all 16B direct loads
__global__ __launch_bounds__(256) void k_gemm2m(const u16* Gx2, const u16* aoB,
                        const float* rs2, void* out, const int* flag){
  int f = *flag;
  int wid = threadIdx.x>>6, l = threadIdx.x&63;
  int lr = l&15, lg = l>>4;
  int m0 = blockIdx.x*32;
  int row0 = m0 + lr, row1 = m0 + 16 + lr;
  bool hi_ok = (m0+16) < N_NODES;
  const u16* a0p = Gx2 + row0*600;
  const u16* a1p = Gx2 + row1*600;
  f32x4 acc[2][4];
  #pragma unroll
  for(int mi=0;mi<2;mi++)
    #pragma unroll
    for(int ntl=0;ntl<4;ntl++) acc[mi][ntl]=(f32x4){0.f,0.f,0.f,0.f};
  #pragma unroll
  for(int k0=0;k0<600;k0+=32){
    int kb = k0 + lg*8;
    bool kok = (kb+8<=600);
    short8 a0 = kok? ldfragb16(a0p, kb) : frag_zero();
    short8 a1 = (hi_ok && kok)? ldfragb16(a1p, kb) : frag_zero();
    #pragma unroll
    for(int ntl=0;ntl<4;ntl++){
      int j = (ntl*4+wid)*16 + lr;
      short8 b = (j<200 && kok)? ldfragb16(aoB, j*600 + kb) : frag_zero();
      acc[0][ntl] = __builtin_amdgcn_mfma_f32_16x16x32_bf16(a0, b, acc[0][ntl], 0,0,0);
      acc[1][ntl] = __builtin_amdgcn_mfma_f32_16x16x32_bf16(a1, b, acc[1][ntl], 0,0,0);
    }
  }
  #pragma unroll
  for(int mi=0;mi<2;mi++){
    if(mi==1 && !hi_ok) break;
    #pragma unroll
    for(int r=0;r<4;r++){
      int rr = m0 + mi*16 + lg*4 + r;
      float sc = (rs2[rr]==0.f)? 0.f : 1.f;
      #pragma unroll
      for(int ntl=0;ntl<4;ntl++){
        int j = (ntl*4+wid)*16 + lr;
        if(j<200) st1(out, rr*200 + j, eluf(acc[mi][ntl][r]*sc), f);
      }
    }
  }
}

extern "C" void kernel_launch(void* const* d_in, const int* in_sizes, int n_in,
                              void* d_out, int out_size, void* d_ws, size_t ws_size,
                              hipStream_t stream) {
  const void* ent = d_in[0];
  const void* rel = d_in[1];
  const int* el  = (const int*)d_in[2];
  const int* et  = (const int*)d_in[3];
  const void* ee  = d_in[4];
  const int* eln = (const int*)d_in[5];
  const int* etn = (const int*)d_in[6];
  const void* ah  = d_in[8];
  const void* a2h = d_in[9];
  const void* W   = d_in[10];
  const void* ao  = d_in[11];
  const void* a2o = d_in[12];

  float* wsf    = (float*)d_ws;
  int*   flag   = (int*)wsf;            // @0 (4 floats reserved)
  float* outrel = wsf+4;                // 40000
  float* b1     = wsf+40008;            // 600
  float* b2     = wsf+40608;            // 600
  float* c1     = wsf+41208;            // 400
  float* c2     = wsf+41608;            // 200
  float* q1     = wsf+41808;            // 120000
  float* q2     = wsf+161808;           // 60000
  float* w1c    = wsf+221808;           // 360000 (CSR-ordered float2 pairs)
  float* w2c    = wsf+581808;           // 180000 (CSR-ordered)
  float* rs1    = wsf+761808;           // 60000
  float* rs2    = wsf+821808;           // 30000
  int*   ofs    = (int*)(wsf+851808);   // 30001
  int*   cnt    = ofs+30001;            // 30000
  int*   cur    = cnt+30000;            // 30000
  int*   bsum   = (int*)(wsf+1121812);  // 128
  int*   bstart = bsum+128;             // 128 -> ends @ 1122068
  u16*   G      = (u16*)(wsf+1122072);  // G1: 12,000,000 u16 -> ends @ 7122072
  int*   pos    = (int*)(wsf+7122072);  // 180000 -> ends @ 7302072
  int4*  einfo  = (int4*)(wsf+7302072); // 180000 int4 -> ends @ 8022072 (16B aligned)
  u16*   entB   = (u16*)(wsf+10122072); // 3,000,000 u16 -> ends @ 11622072
  u16*   ahB    = (u16*)(wsf+11622072); // 60,000 u16 -> ends @ 11652072
  u16*   aoB    = (u16*)(wsf+11652072); // 120,000 u16 -> ends @ 11712072
  u16*   eeB    = (u16*)(wsf+11712072); // 15,000,000 u16
  // Gx2 (18M u16 = [h|v|w] rows of 600) ALIASES eeB region: eeB's last reader (k_acc1)
  // completes before k_gemm1m writes Gx2 (stream-ordered).
  u16*   Gx2    = (u16*)(wsf+11712072); // 18,000,000 u16 -> ends @ float 20712072 (~82.9 MB)
  int ws_ok = (ws_size >= (size_t)20712072*4) ? 1 : 0;

  const int* src1 = el;
  const int* dst1 = el + E1;
  const int* srcN = eln;
  const int* dstN = eln + EN;

  k_detect<<<1,256,0,stream>>>((const u32*)ent, flag);
  hipMemsetAsync(cnt, 0, 30000*sizeof(int), stream);
  k_prep<<<2048,256,0,stream>>>(ent, ah, ao, ee, entB, ahB, aoB, eeB, ws_ok, flag);
  k_small_b<<<300,256,0,stream>>>(ah,a2h,ao,a2o,b1,b2,flag);
  k_outrel<<<(200*200+255)/256,256,0,stream>>>(rel, W, outrel, d_out, flag);
  k_small_c<<<150,256,0,stream>>>(rel, outrel, b1, b2, c1, c2, flag);
  k_count<<<(ET+255)/256,256,0,stream>>>(src1, srcN, cnt);
  k_scan1<<<NB_SCAN,256,0,stream>>>(cnt, ofs, bsum);
  k_scan2<<<1,128,0,stream>>>(bsum, bstart, ofs);
  k_scan3<<<NB_SCAN,256,0,stream>>>(ofs, cur, bstart);
  k_scatter<<<(ET+255)/256,256,0,stream>>>(src1, dst1, srcN, dstN, et, etn, cur, pos, einfo);
  k_q1<<<(N_NODES+3)/4,256,0,stream>>>((const u32*)entB, b1, q1);
  k_edge1g<<<(E1+127)/128,256,0,stream>>>(ee, eeB, ws_ok, src1, dst1, b1, q1, pos, w1c, flag);
  k_edge1b<<<(EN+255)/256,256,0,stream>>>(etn, srcN, dstN, c1, q1, pos, w1c);
  k_acc1<<<(N_NODES+3)/4,256,0,stream>>>(ofs, einfo,
                                         (const u32*)entB, ee, (const u32*)eeB, ws_ok,
                                         rel, (const float2*)w1c, (u32*)G, rs1, flag);
  dim3 g1grid((N_NODES+31)/32, 2);
  k_gemm1m<<<g1grid,256,0,stream>>>(G, ahB, entB, rs1, Gx2);
  k_q2<<<(N_NODES+3)/4,256,0,stream>>>((const uint2*)Gx2, b2, q2);
  k_edge2<<<(ET+255)/256,256,0,stream>>>(src1, dst1, srcN, dstN, et, etn, c2, q2, pos, w2c);
  k_acc2<<<(N_NODES+3)/4,256,0,stream>>>(ofs, einfo,
                                         (u32*)Gx2, (const float4*)outrel, w2c, rs2);
  k_gemm2m<<<(N_NODES+31)/32,256,0,stream>>>(Gx2, aoB, rs2, d_out, flag);
}

// Round 19
// 244.524 us; speedup vs baseline: 1.1424x; 1.0009x over previous
//
#include <hip/hip_runtime.h>

#define N_NODES 30000
#define E1 150000
#define EN 30000
#define ET 180000
#define LALPHA 0.2f
#define NB_SCAN 118

typedef unsigned int u32;
typedef unsigned short u16;
typedef __attribute__((ext_vector_type(8))) short short8;
typedef __attribute__((ext_vector_type(4))) short short4v;
typedef __attribute__((ext_vector_type(4))) float f32x4;

__device__ __forceinline__ float bf2f(u16 u){ return __uint_as_float(((u32)u)<<16); }
__device__ __forceinline__ float2 bfp2(u32 u){
  return make_float2(__uint_as_float(u<<16), __uint_as_float(u & 0xffff0000u));
}
__device__ __forceinline__ u16 f2bf(float f){
  u32 x = __float_as_uint(f);
  return (u16)((x + 0x7fffu + ((x>>16)&1u)) >> 16);
}
__device__ __forceinline__ u32 pk(float x, float y){
  return ((u32)f2bf(x)) | (((u32)f2bf(y))<<16);
}
__device__ __forceinline__ float wredf(float v){
  #pragma unroll
  for(int o=32;o>0;o>>=1) v += __shfl_xor(v, o, 64);
  return v;
}
__device__ __forceinline__ float eluf(float y){ return (y>0.f)? y : expm1f(y); }
// dtype dispatch: f==1 -> buffers are f32; f==0 -> packed bf16
__device__ __forceinline__ float ld1(const void* p, int i, int f){
  return f ? ((const float*)p)[i] : bf2f(((const u16*)p)[i]);
}
__device__ __forceinline__ float2 ldp(const void* p, int i, int f){ // elements 2i,2i+1
  if(f){ return ((const float2*)p)[i]; }
  return bfp2(((const u32*)p)[i]);
}
__device__ __forceinline__ void st1(void* p, int i, float v, int f){
  if(f) ((float*)p)[i] = v; else ((u16*)p)[i] = f2bf(v);
}

__device__ __forceinline__ short8 frag_zero(){
  short8 r;
  #pragma unroll
  for(int i=0;i<8;i++) r[i]=0;
  return r;
}
// packed-bf16 fragment load (8 consecutive bf16, 2x8B vector loads)
__device__ __forceinline__ short8 ldfragb(const u16* p, int idx){
  short8 r;
  short4v lo = *(const short4v*)(p+idx);
  short4v hi = *(const short4v*)(p+idx+4);
  #pragma unroll
  for(int i=0;i<4;i++){ r[i]=lo[i]; r[4+i]=hi[i]; }
  return r;
}
// 16B-aligned fragment load (one dwordx4)
__device__ __forceinline__ short8 ldfragb16(const u16* p, int idx){
  return *(const short8*)(p+idx);
}
__device__ __forceinline__ short8 ldfragb_p4(const u16* p, int idx){
  short8 r=frag_zero();
  short4v lo = *(const short4v*)(p+idx);
  #pragma unroll
  for(int i=0;i<4;i++) r[i]=lo[i];
  return r;
}
// dual-dtype fragment loads (f32 path: contiguous scalar loads, compiler merges)
__device__ __forceinline__ short8 ldfrag(const void* p, int idx, int f){
  short8 r;
  if(f){
    const float* fp=(const float*)p+idx;
    #pragma unroll
    for(int i=0;i<8;i++) r[i]=(short)f2bf(fp[i]);
  } else {
    return ldfragb((const u16*)p, idx);
  }
  return r;
}
__device__ __forceinline__ short8 ldfrag_p4(const void* p, int idx, int f){
  short8 r=frag_zero();
  if(f){
    const float* fp=(const float*)p+idx;
    #pragma unroll
    for(int i=0;i<4;i++) r[i]=(short)f2bf(fp[i]);
  } else {
    return ldfragb_p4((const u16*)p, idx);
  }
  return r;
}

// Detect dtype: for bf16-packed data, low u16 of each u32 is a bf16 of ~N(0,1)
__global__ void k_detect(const u32* x, int* flag){
  int t = threadIdx.x;
  int c = 0;
  #pragma unroll
  for(int i=0;i<4;i++){
    u32 v = x[t*4+i];
    u32 lo = v & 0xffffu;
    u32 e = (lo>>7)&0xffu;
    c += (lo==0u || (e>=100u && e<=140u)) ? 1 : 0;
  }
  __shared__ int sd[256];
  sd[t]=c; __syncthreads();
  for(int o=128;o>0;o>>=1){ if(t<o) sd[t]+=sd[t+o]; __syncthreads(); }
  if(t==0) *flag = (sd[0] > 512) ? 0 : 1;
}

// one-time bf16 pre-pack: ent (3M), ah (60K), ao (120K), and (f32 case) ee (15M)
__global__ void k_prep(const void* ent, const void* ah, const void* ao, const void* ee,
                       u16* entB, u16* ahB, u16* aoB, u16* eeB, int ws_ok, const int* flag){
  int f = *flag;
  int gid = blockIdx.x*256 + threadIdx.x;
  int stride = gridDim.x*256;
  const int T0=750000, T1=765000, T2=795000, T3=795000+3750000; // 4-elem groups
  int lim = (f && ws_ok) ? T3 : T2;
  for(int i=gid; i<lim; i+=stride){
    const void* src; u16* dst; int g;
    if(i<T0){ src=ent; dst=entB; g=i; }
    else if(i<T1){ src=ah; dst=ahB; g=i-T0; }
    else if(i<T2){ src=ao; dst=aoB; g=i-T1; }
    else { src=ee; dst=eeB; g=i-T2; }
    if(f){
      float4 v = ((const float4*)src)[g];
      short4v o;
      o[0]=(short)f2bf(v.x); o[1]=(short)f2bf(v.y);
      o[2]=(short)f2bf(v.z); o[3]=(short)f2bf(v.w);
      ((short4v*)dst)[g] = o;
    } else {
      ((short4v*)dst)[g] = ((const short4v*)src)[g];
    }
  }
}

// out_relation = relation_embed @ W  (200x100)@(100x200): f32 ws + tail of d_out
__global__ void k_outrel(const void* rel, const void* W, float* outrel, void* out, const int* flag){
  int f = *flag;
  int t = blockIdx.x*blockDim.x + threadIdx.x;
  if(t >= 200*200) return;
  int r = t / 200, j = t - r*200;
  float acc = 0.f;
  for(int k=0;k<100;k++) acc += ld1(rel, r*100+k, f) * ld1(W, k*200+j, f);
  outrel[t] = acc;
  st1(out, 6000000 + t, acc, f);
}

// b1[i<600]: b1[hd*300+k] = sum_j a2h[hd][j]*ah[hd][j][k]
// b2[i-600]: b2[k] = sum_j a2o[j]*ao[j][k]   (k<600)
__global__ void k_small_b(const void* ah, const void* a2h, const void* ao, const void* a2o,
                          float* b1, float* b2, const int* flag){
  int f = *flag;
  int i = blockIdx.x*4 + (threadIdx.x>>6);
  int L = threadIdx.x & 63;
  if(i >= 1200) return;
  float a = 0.f;
  if(i < 600){
    int hd = i/300, k = i - hd*300;
    for(int j=L; j<100; j+=64)
      a += ld1(a2h, hd*100+j, f) * ld1(ah, hd*30000 + j*300 + k, f);
    a = wredf(a);
    if(L==0) b1[i] = a;
  } else {
    int k = i - 600;
    for(int j=L; j<200; j+=64)
      a += ld1(a2o, j, f) * ld1(ao, j*600 + k, f);
    a = wredf(a);
    if(L==0) b2[k] = a;
  }
}

// c1[i<400]: c1[hd*200+r] = sum_k b1[hd*300+200+k]*rel[r][k]
// c2[i-400]: c2[r] = sum_k b2[400+k]*outrel[r][k]
__global__ void k_small_c(const void* rel, const float* outrel, const float* b1, const float* b2,
                          float* c1, float* c2, const int* flag){
  int f = *flag;
  int i = blockIdx.x*4 + (threadIdx.x>>6);
  int L = threadIdx.x & 63;
  if(i >= 600) return;
  float a = 0.f;
  if(i < 400){
    int hd = i/200, r = i - hd*200;
    for(int k=L; k<100; k+=64)
      a += b1[hd*300+200+k] * ld1(rel, r*100+k, f);
    a = wredf(a);
    if(L==0) c1[i] = a;
  } else {
    int r = i - 400;
    for(int k=L; k<200; k+=64)
      a += b2[400+k] * outrel[r*200+k];
    a = wredf(a);
    if(L==0) c2[r] = a;
  }
}

__global__ void k_count(const int* src1, const int* srcN, int* cnt){
  int e = blockIdx.x*256 + threadIdx.x;
  if(e>=ET) return;
  int s = (e<E1)? src1[e] : srcN[e-E1];
  atomicAdd(&cnt[s],1);
}

// two-level scan: per-block scan -> block sums scan -> fixup
__global__ void k_scan1(const int* cnt, int* ofs, int* bsum){
  __shared__ int sd[256];
  int b=blockIdx.x, t=threadIdx.x;
  int idx=b*256+t;
  int v=(idx<N_NODES)? cnt[idx] : 0;
  sd[t]=v; __syncthreads();
  for(int o=1;o<256;o<<=1){
    int u=(t>=o)? sd[t-o]:0;
    __syncthreads();
    sd[t]+=u; __syncthreads();
  }
  if(idx<N_NODES) ofs[idx]=sd[t]-v;
  if(t==255) bsum[b]=sd[255];
}

__global__ void k_scan2(const int* bsum, int* bstart, int* ofs){
  __shared__ int sd[128];
  int t=threadIdx.x;
  int v=(t<NB_SCAN)? bsum[t]:0;
  sd[t]=v; __syncthreads();
  for(int o=1;o<128;o<<=1){
    int u=(t>=o)? sd[t-o]:0;
    __syncthreads();
    sd[t]+=u; __syncthreads();
  }
  if(t<NB_SCAN) bstart[t]=sd[t]-v;
  if(t==127) ofs[N_NODES]=sd[127];
}

__global__ void k_scan3(int* ofs, int* cur, const int* bstart){
  int b=blockIdx.x, t=threadIdx.x;
  int idx=b*256+t;
  if(idx>=N_NODES) return;
  int v = ofs[idx] + bstart[b];
  ofs[idx]=v; cur[idx]=v;
}

// scatter + CSR side tables: einfo[p]=(e,d,t0,t1) (t1=-1 for orig), pos[e]=p
__global__ void k_scatter(const int* src1, const int* dst1, const int* srcN, const int* dstN,
                          const int* et, const int* etn, int* cur, int* pos, int4* einfo){
  int e = blockIdx.x*256 + threadIdx.x;
  if(e>=ET) return;
  int s,d,t0,t1;
  if(e<E1){ s=src1[e]; d=dst1[e]; t0=et[e]; t1=-1; }
  else { int en=e-E1; s=srcN[en]; d=dstN[en]; t0=etn[en*2]; t1=etn[en*2+1]; }
  int p = atomicAdd(&cur[s],1);
  pos[e]=p;
  einfo[p]=make_int4(e,d,t0,t1);
}

// per-node dots layer1 (bf16 node features): q1[n*4 + {h0s,h0d,h1s,h1d}]
__global__ void k_q1(const u32* entB2, const float* b1, float* q1){
  int n = blockIdx.x*4 + (threadIdx.x>>6);
  if(n>=N_NODES) return;
  int L = threadIdx.x & 63;
  float d00=0,d01=0,d10=0,d11=0;
  if(L<50){
    float2 xv = bfp2(entB2[n*50+L]);
    int k0=2*L;
    d00 = xv.x*b1[k0]     + xv.y*b1[k0+1];
    d01 = xv.x*b1[100+k0] + xv.y*b1[100+k0+1];
    d10 = xv.x*b1[300+k0] + xv.y*b1[300+k0+1];
    d11 = xv.x*b1[400+k0] + xv.y*b1[400+k0+1];
  }
  d00=wredf(d00); d01=wredf(d01); d10=wredf(d10); d11=wredf(d11);
  if(L==0){ q1[n*4+0]=d00; q1[n*4+1]=d01; q1[n*4+2]=d10; q1[n*4+3]=d11; }
}

// layer1 edge logits for original edges: MFMA GEMV, 32 edges/wave, writes w1c in CSR order
__global__ __launch_bounds__(256) void k_edge1g(const void* ee, const u16* eeB, int ws_ok,
    const int* src1, const int* dst1, const float* b1, const float* q1,
    const int* pos, float* w1c, const int* flag){
  int f = *flag;
  const void* eeP = (f && ws_ok) ? (const void*)eeB : ee;
  int fe = (f && ws_ok) ? 0 : f;
  int wid = threadIdx.x>>6, l = threadIdx.x&63;
  int lr = l&15, lg = l>>4;
  int m0 = blockIdx.x*128 + wid*32;
  short8 bfr[4];
  #pragma unroll
  for(int ks=0;ks<4;ks++){
    int kb = ks*32 + lg*8;
    short8 b = frag_zero();
    if(lr<2){
      const float* bp = b1 + (lr==0? 200:500);
      #pragma unroll
      for(int i=0;i<8;i++){ int k=kb+i; if(k<100) b[i]=(short)f2bf(bp[k]); }
    }
    bfr[ks]=b;
  }
  int row0 = m0 + lr, row1 = m0 + 16 + lr;
  bool ok0 = row0 < E1, ok1 = row1 < E1;
  f32x4 acc0=(f32x4){0,0,0,0}, acc1=(f32x4){0,0,0,0};
  #pragma unroll
  for(int ks=0;ks<4;ks++){
    int kb = ks*32 + lg*8;
    short8 a0 = frag_zero(), a1 = frag_zero();
    if(ok0){
      if(kb+8<=100) a0 = ldfrag(eeP, row0*100+kb, fe);
      else if(kb<100) a0 = ldfrag_p4(eeP, row0*100+kb, fe);
    }
    if(ok1){
      if(kb+8<=100) a1 = ldfrag(eeP, row1*100+kb, fe);
      else if(kb<100) a1 = ldfrag_p4(eeP, row1*100+kb, fe);
    }
    acc0 = __builtin_amdgcn_mfma_f32_16x16x32_bf16(a0, bfr[ks], acc0, 0,0,0);
    acc1 = __builtin_amdgcn_mfma_f32_16x16x32_bf16(a1, bfr[ks], acc1, 0,0,0);
  }
  if(lr<2){
    #pragma unroll
    for(int mi=0;mi<2;mi++){
      #pragma unroll
      for(int r=0;r<4;r++){
        int e = m0 + mi*16 + lg*4 + r;
        if(e<E1){
          float rv = (mi==0)? acc0[r] : acc1[r];
          int s=src1[e], d=dst1[e];
          float p = q1[s*4+lr*2] + q1[d*4+lr*2+1] + rv;
          p = (p>=0.f)? p : LALPHA*p;
          w1c[2*pos[e] + lr] = expf(-p);
        }
      }
    }
  }
}

// layer1 edge logits for nhop edges (CSR-ordered writes)
__global__ void k_edge1b(const int* etn, const int* srcN, const int* dstN,
                         const float* c1, const float* q1, const int* pos, float* w1c){
  int en = blockIdx.x*256+threadIdx.x;
  if(en>=EN) return;
  int t0=etn[en*2], t1=etn[en*2+1];
  float r0 = c1[t0]+c1[t1];
  float r1 = c1[200+t0]+c1[200+t1];
  int s=srcN[en], d=dstN[en];
  float p0 = q1[s*4+0]+q1[d*4+1]+r0;
  float p1 = q1[s*4+2]+q1[d*4+3]+r1;
  p0=(p0>=0.f)?p0:LALPHA*p0;
  p1=(p1>=0.f)?p1:LALPHA*p1;
  int p = pos[E1+en];
  w1c[2*p]   = expf(-p0);
  w1c[2*p+1] = expf(-p1);
}

// layer1 gather (einfo-driven, x4 unroll): G1[hd][n][200]
__global__ void k_acc1(const int* ofs, const int4* einfo,
                       const u32* entB2, const void* ee, const u32* eeB32, int ws_ok,
                       const void* rel,
                       const float2* w1c, u32* Gq, float* rs1, const int* flag){
  int f = *flag;
  int use_pack = (f==1) && ws_ok;
  int n = blockIdx.x*4 + (threadIdx.x>>6);
  if(n>=N_NODES) return;
  int L = threadIdx.x & 63;
  int beg = ofs[n], end = ofs[n+1];
  float av0x=0,av0y=0,av1x=0,av1y=0, aw0x=0,aw0y=0,aw1x=0,aw1y=0;
  float r0=0, r1=0;
  int i = beg;
  for(; i+3<end; i+=4){
    int4 ei[4]; float2 w[4];
    #pragma unroll
    for(int u=0;u<4;u++) ei[u]=einfo[i+u];
    #pragma unroll
    for(int u=0;u<4;u++) w[u]=w1c[i+u];
    r0 += w[0].x+w[1].x+w[2].x+w[3].x;
    r1 += w[0].y+w[1].y+w[2].y+w[3].y;
    if(L<50){
      float2 xv[4], vv[4];
      #pragma unroll
      for(int u=0;u<4;u++) xv[u]=bfp2(entB2[ei[u].y*50+L]);
      #pragma unroll
      for(int u=0;u<4;u++){
        if(ei[u].x < E1){
          vv[u] = use_pack? bfp2(eeB32[ei[u].x*50+L]) : ldp(ee, ei[u].x*50+L, f);
        } else {
          float2 a=ldp(rel,ei[u].z*50+L,f), b=ldp(rel,ei[u].w*50+L,f);
          vv[u]=make_float2(a.x+b.x, a.y+b.y);
        }
      }
      #pragma unroll
      for(int u=0;u<4;u++){
        av0x += w[u].x*xv[u].x; av0y += w[u].x*xv[u].y;
        av1x += w[u].y*xv[u].x; av1y += w[u].y*xv[u].y;
        aw0x += w[u].x*vv[u].x; aw0y += w[u].x*vv[u].y;
        aw1x += w[u].y*vv[u].x; aw1y += w[u].y*vv[u].y;
      }
    }
  }
  for(; i<end; ++i){
    int4 ei = einfo[i];
    float2 wa = w1c[i];
    r0 += wa.x; r1 += wa.y;
    if(L<50){
      float2 x0 = bfp2(entB2[ei.y*50+L]);
      float2 v0;
      if(ei.x < E1){ v0 = use_pack? bfp2(eeB32[ei.x*50+L]) : ldp(ee, ei.x*50+L, f); }
      else {
        float2 a=ldp(rel,ei.z*50+L,f), b=ldp(rel,ei.w*50+L,f);
        v0=make_float2(a.x+b.x, a.y+b.y);
      }
      av0x += wa.x*x0.x; av0y += wa.x*x0.y;
      av1x += wa.y*x0.x; av1y += wa.y*x0.y;
      aw0x += wa.x*v0.x; aw0y += wa.x*v0.y;
      aw1x += wa.y*v0.x; aw1y += wa.y*v0.y;
    }
  }
  float i0 = (r0==0.f)? 0.f : 1.f/r0;
  float i1 = (r1==0.f)? 0.f : 1.f/r1;
  if(L<50){
    u32* g0 = Gq + n*100;
    u32* g1 = Gq + 3000000 + n*100;
    g0[L]    = pk(av0x*i0, av0y*i0);
    g0[50+L] = pk(aw0x*i0, aw0y*i0);
    g1[L]    = pk(av1x*i1, av1y*i1);
    g1[50+L] = pk(aw1x*i1, aw1y*i1);
  }
  if(L==0){ rs1[n]=r0; rs1[N_NODES+n]=r1; }
}

// MFMA node GEMM layer1, M=32/block, N-split across waves; h written into Gx2 rows [0..200)
__global__ __launch_bounds__(256) void k_gemm1m(const u16* G, const u16* ahB, const u16* entB,
                        const float* rs1, u16* Gx2){
  int hd = blockIdx.y;
  int wid = threadIdx.x>>6, l = threadIdx.x&63;
  int lr = l&15, lg = l>>4;
  int m0 = blockIdx.x*32;
  int row0 = m0 + lr, row1 = m0 + 16 + lr;
  bool hi_ok = (m0+16) < N_NODES;
  const u16* Gh0 = G + hd*6000000 + row0*200;
  const u16* Gh1 = G + hd*6000000 + row1*200;
  const u16* A = ahB + hd*30000;
  f32x4 acc[2][2];
  #pragma unroll
  for(int mi=0;mi<2;mi++)
    #pragma unroll
    for(int ntl=0;ntl<2;ntl++) acc[mi][ntl]=(f32x4){0.f,0.f,0.f,0.f};
  #pragma unroll
  for(int k0=0;k0<100;k0+=32){
    int kb = k0 + lg*8;
    short8 a0 = (kb+8<=100)? ldfragb(entB, row0*100+kb)
              : (kb<100    ? ldfragb_p4(entB, row0*100+kb) : frag_zero());
    short8 a1 = frag_zero();
    if(hi_ok){
      if(kb+8<=100) a1 = ldfragb(entB, row1*100+kb);
      else if(kb<100) a1 = ldfragb_p4(entB, row1*100+kb);
    }
    #pragma unroll
    for(int ntl=0;ntl<2;ntl++){
      int j = (ntl*4+wid)*16 + lr;
      short8 b = frag_zero();
      if(j<100){
        if(kb+8<=100) b = ldfragb(A, j*300 + kb);
        else if(kb<100) b = ldfragb_p4(A, j*300 + kb);
      }
      acc[0][ntl] = __builtin_amdgcn_mfma_f32_16x16x32_bf16(a0, b, acc[0][ntl], 0,0,0);
      acc[1][ntl] = __builtin_amdgcn_mfma_f32_16x16x32_bf16(a1, b, acc[1][ntl], 0,0,0);
    }
  }
  #pragma unroll
  for(int k0=0;k0<200;k0+=32){
    int kb = k0 + lg*8;
    short8 a0 = (kb+8<=200)? ldfragb(Gh0, kb) : frag_zero();
    short8 a1 = (hi_ok && kb+8<=200)? ldfragb(Gh1, kb) : frag_zero();
    #pragma unroll
    for(int ntl=0;ntl<2;ntl++){
      int j = (ntl*4+wid)*16 + lr;
      short8 b = (j<100 && kb+8<=200)? ldfragb(A, j*300 + 100 + kb) : frag_zero();
      acc[0][ntl] = __builtin_amdgcn_mfma_f32_16x16x32_bf16(a0, b, acc[0][ntl], 0,0,0);
      acc[1][ntl] = __builtin_amdgcn_mfma_f32_16x16x32_bf16(a1, b, acc[1][ntl], 0,0,0);
    }
  }
  #pragma unroll
  for(int mi=0;mi<2;mi++){
    if(mi==1 && !hi_ok) break;
    #pragma unroll
    for(int r=0;r<4;r++){
      int rr = m0 + mi*16 + lg*4 + r;
      float sc = (rs1[hd*N_NODES+rr]==0.f)? 0.f : 1.f;
      #pragma unroll
      for(int ntl=0;ntl<2;ntl++){
        int j = (ntl*4+wid)*16 + lr;
        if(j<100) Gx2[rr*600 + hd*100 + j] = f2bf(eluf(acc[mi][ntl][r]*sc));
      }
    }
  }
}

// q2 over h stored in Gx2 rows [0..200)
__global__ void k_q2(const uint2* hq, const float* b2, float* q2){
  int n = blockIdx.x*4 + (threadIdx.x>>6);
  if(n>=N_NODES) return;
  int L = threadIdx.x&63;
  float ds=0, dd=0;
  if(L<50){
    uint2 hv = hq[n*150+L];
    float2 a = bfp2(hv.x);
    float2 b = bfp2(hv.y);
    int k0=4*L;
    ds = a.x*b2[k0]+a.y*b2[k0+1]+b.x*b2[k0+2]+b.y*b2[k0+3];
    dd = a.x*b2[200+k0]+a.y*b2[200+k0+1]+b.x*b2[200+k0+2]+b.y*b2[200+k0+3];
  }
  ds=wredf(ds); dd=wredf(dd);
  if(L==0){ q2[n*2]=ds; q2[n*2+1]=dd; }
}

// layer2 gather with FUSED edge weights (edge2 absorbed): w computed inline from
// q2/c2 via einfo (slot's src == n). Writes Gx2 rows [200..600).
__global__ void k_acc2(const int* ofs, const int4* einfo,
                       u32* Gx2u, const float4* or4, const float* c2, const float* q2,
                       float* rs2){
  const uint2* h2 = (const uint2*)Gx2u;
  int n = blockIdx.x*4 + (threadIdx.x>>6);
  if(n>=N_NODES) return;
  int L = threadIdx.x&63;
  int beg=ofs[n], end=ofs[n+1];
  float q2n = q2[n*2];
  float rv=0;
  float avx=0,avy=0,avz=0,avw=0, awx=0,awy=0,awz=0,aww=0;
  int i=beg;
  for(; i+3<end; i+=4){
    int4 ei[4]; float wv[4];
    #pragma unroll
    for(int u=0;u<4;u++) ei[u]=einfo[i+u];
    #pragma unroll
    for(int u=0;u<4;u++){
      float r = c2[ei[u].z];
      if(ei[u].w >= 0) r += c2[ei[u].w];
      float p = q2n + q2[ei[u].y*2+1] + r;
      p = (p>=0.f)? p : LALPHA*p;
      wv[u] = expf(-p);
    }
    rv += wv[0]+wv[1]+wv[2]+wv[3];
    if(L<50){
      float2 ha[4], hb[4]; float4 o[4];
      #pragma unroll
      for(int u=0;u<4;u++){ uint2 hv = h2[ei[u].y*150+L]; ha[u]=bfp2(hv.x); hb[u]=bfp2(hv.y); }
      #pragma unroll
      for(int u=0;u<4;u++){
        float4 a = or4[ei[u].z*50+L];
        if(ei[u].w >= 0){
          float4 b = or4[ei[u].w*50+L];
          a = make_float4(a.x+b.x, a.y+b.y, a.z+b.z, a.w+b.w);
        }
        o[u]=a;
      }
      #pragma unroll
      for(int u=0;u<4;u++){
        avx += wv[u]*ha[u].x; avy += wv[u]*ha[u].y;
        avz += wv[u]*hb[u].x; avw += wv[u]*hb[u].y;
        awx += wv[u]*o[u].x;  awy += wv[u]*o[u].y;
        awz += wv[u]*o[u].z;  aww += wv[u]*o[u].w;
      }
    }
  }
  for(; i<end; ++i){
    int4 ei = einfo[i];
    float r = c2[ei.z];
    if(ei.w >= 0) r += c2[ei.w];
    float p = q2n + q2[ei.y*2+1] + r;
    p = (p>=0.f)? p : LALPHA*p;
    float w0 = expf(-p);
    rv += w0;
    if(L<50){
      uint2 hv = h2[ei.y*150+L];
      float2 ha0=bfp2(hv.x), hb0=bfp2(hv.y);
      float4 o0 = or4[ei.z*50+L];
      if(ei.w >= 0){
        float4 b = or4[ei.w*50+L];
        o0 = make_float4(o0.x+b.x, o0.y+b.y, o0.z+b.z, o0.w+b.w);
      }
      avx += w0*ha0.x; avy += w0*ha0.y; avz += w0*hb0.x; avw += w0*hb0.y;
      awx += w0*o0.x; awy += w0*o0.y; awz += w0*o0.z; aww += w0*o0.w;
    }
  }
  float inv = (rv==0.f)? 0.f : 1.f/rv;
  if(L<50){
    u32* g = Gx2u + n*300 + 100;
    g[2*L]       = pk(avx*inv, avy*inv);
    g[2*L+1]     = pk(avz*inv, avw*inv);
    g[100+2*L]   = pk(awx*inv, awy*inv);
    g[100+2*L+1] = pk(awz*inv, aww*inv);
  }
  if(L==0) rs2[n]=rv;
}

// MFMA node GEMM layer2, M=32/block, single contiguous K=600: all 16B direct loads
__global__ __launch_bounds__(256) void k_gemm2m(const u16* Gx2, const u16* aoB,
                        const float* rs2, void* out, const int* flag){
  int f = *flag;
  int wid = threadIdx.x>>6, l = threadIdx.x&63;
  int lr = l&15, lg = l>>4;
  int m0 = blockIdx.x*32;
  int row0 = m0 + lr, row1 = m0 + 16 + lr;
  bool hi_ok = (m0+16) < N_NODES;
  const u16* a0p = Gx2 + row0*600;
  const u16* a1p = Gx2 + row1*600;
  f32x4 acc[2][4];
  #pragma unroll
  for(int mi=0;mi<2;mi++)
    #pragma unroll
    for(int ntl=0;ntl<4;ntl++) acc[mi][ntl]=(f32x4){0.f,0.f,0.f,0.f};
  #pragma unroll
  for(int k0=0;k0<600;k0+=32){
    int kb = k0 + lg*8;
    bool kok = (kb+8<=600);
    short8 a0 = kok? ldfragb16(a0p, kb) : frag_zero();
    short8 a1 = (hi_ok && kok)? ldfragb16(a1p, kb) : frag_zero();
    #pragma unroll
    for(int ntl=0;ntl<4;ntl++){
      int j = (ntl*4+wid)*16 + lr;
      short8 b = (j<200 && kok)? ldfragb16(aoB, j*600 + kb) : frag_zero();
      acc[0][ntl] = __builtin_amdgcn_mfma_f32_16x16x32_bf16(a0, b, acc[0][ntl], 0,0,0);
      acc[1][ntl] = __builtin_amdgcn_mfma_f32_16x16x32_bf16(a1, b, acc[1][ntl], 0,0,0);
    }
  }
  #pragma unroll
  for(int mi=0;mi<2;mi++){
    if(mi==1 && !hi_ok) break;
    #pragma unroll
    for(int r=0;r<4;r++){
      int rr = m0 + mi*16 + lg*4 + r;
      float sc = (rs2[rr]==0.f)? 0.f : 1.f;
      #pragma unroll
      for(int ntl=0;ntl<4;ntl++){
        int j = (ntl*4+wid)*16 + lr;
        if(j<200) st1(out, rr*200 + j, eluf(acc[mi][ntl][r]*sc), f);
      }
    }
  }
}

extern "C" void kernel_launch(void* const* d_in, const int* in_sizes, int n_in,
                              void* d_out, int out_size, void* d_ws, size_t ws_size,
                              hipStream_t stream) {
  const void* ent = d_in[0];
  const void* rel = d_in[1];
  const int* el  = (const int*)d_in[2];
  const int* et  = (const int*)d_in[3];
  const void* ee  = d_in[4];
  const int* eln = (const int*)d_in[5];
  const int* etn = (const int*)d_in[6];
  const void* ah  = d_in[8];
  const void* a2h = d_in[9];
  const void* W   = d_in[10];
  const void* ao  = d_in[11];
  const void* a2o = d_in[12];

  float* wsf    = (float*)d_ws;
  int*   flag   = (int*)wsf;            // @0 (4 floats reserved)
  float* outrel = wsf+4;                // 40000
  float* b1     = wsf+40008;            // 600
  float* b2     = wsf+40608;            // 600
  float* c1     = wsf+41208;            // 400
  float* c2     = wsf+41608;            // 200
  float* q1     = wsf+41808;            // 120000
  float* q2     = wsf+161808;           // 60000
  float* w1c    = wsf+221808;           // 360000 (CSR-ordered float2 pairs)
  float* rs1    = wsf+761808;           // 60000
  float* rs2    = wsf+821808;           // 30000
  int*   ofs    = (int*)(wsf+851808);   // 30001
  int*   cnt    = ofs+30001;            // 30000
  int*   cur    = cnt+30000;            // 30000
  int*   bsum   = (int*)(wsf+1121812);  // 128
  int*   bstart = bsum+128;             // 128 -> ends @ 1122068
  u16*   G      = (u16*)(wsf+1122072);  // G1: 12,000,000 u16 -> ends @ 7122072
  int*   pos    = (int*)(wsf+7122072);  // 180000 -> ends @ 7302072
  int4*  einfo  = (int4*)(wsf+7302072); // 180000 int4 -> ends @ 8022072 (16B aligned)
  u16*   entB   = (u16*)(wsf+10122072); // 3,000,000 u16 -> ends @ 11622072
  u16*   ahB    = (u16*)(wsf+11622072); // 60,000 u16 -> ends @ 11652072
  u16*   aoB    = (u16*)(wsf+11652072); // 120,000 u16 -> ends @ 11712072
  u16*   eeB    = (u16*)(wsf+11712072); // 15,000,000 u16
  // Gx2 (18M u16 = [h|v|w] rows of 600) ALIASES eeB region: eeB's last reader (k_acc1)
  // completes before k_gemm1m writes Gx2 (stream-ordered).
  u16*   Gx2    = (u16*)(wsf+11712072); // 18,000,000 u16 -> ends @ float 20712072 (~82.9 MB)
  int ws_ok = (ws_size >= (size_t)20712072*4) ? 1 : 0;

  const int* src1 = el;
  const int* dst1 = el + E1;
  const int* srcN = eln;
  const int* dstN = eln + EN;

  k_detect<<<1,256,0,stream>>>((const u32*)ent, flag);
  hipMemsetAsync(cnt, 0, 30000*sizeof(int), stream);
  k_prep<<<2048,256,0,stream>>>(ent, ah, ao, ee, entB, ahB, aoB, eeB, ws_ok, flag);
  k_small_b<<<300,256,0,stream>>>(ah,a2h,ao,a2o,b1,b2,flag);
  k_outrel<<<(200*200+255)/256,256,0,stream>>>(rel, W, outrel, d_out, flag);
  k_small_c<<<150,256,0,stream>>>(rel, outrel, b1, b2, c1, c2, flag);
  k_count<<<(ET+255)/256,256,0,stream>>>(src1, srcN, cnt);
  k_scan1<<<NB_SCAN,256,0,stream>>>(cnt, ofs, bsum);
  k_scan2<<<1,128,0,stream>>>(bsum, bstart, ofs);
  k_scan3<<<NB_SCAN,256,0,stream>>>(ofs, cur, bstart);
  k_scatter<<<(ET+255)/256,256,0,stream>>>(src1, dst1, srcN, dstN, et, etn, cur, pos, einfo);
  k_q1<<<(N_NODES+3)/4,256,0,stream>>>((const u32*)entB, b1, q1);
  k_edge1g<<<(E1+127)/128,256,0,stream>>>(ee, eeB, ws_ok, src1, dst1, b1, q1, pos, w1c, flag);
  k_edge1b<<<(EN+255)/256,256,0,stream>>>(etn, srcN, dstN, c1, q1, pos, w1c);
  k_acc1<<<(N_NODES+3)/4,256,0,stream>>>(ofs, einfo,
                                         (const u32*)entB, ee, (const u32*)eeB, ws_ok,
                                         rel, (const float2*)w1c, (u32*)G, rs1, flag);
  dim3 g1grid((N_NODES+31)/32, 2);
  k_gemm1m<<<g1grid,256,0,stream>>>(G, ahB, entB, rs1, Gx2);
  k_q2<<<(N_NODES+3)/4,256,0,stream>>>((const uint2*)Gx2, b2, q2);
  k_acc2<<<(N_NODES+3)/4,256,0,stream>>>(ofs, einfo,
                                         (u32*)Gx2, (const float4*)outrel, c2, q2, rs2);
  k_gemm2m<<<(N_NODES+31)/32,256,0,stream>>>(Gx2, aoB, rs2, d_out, flag);
}